// Round 20
// baseline (239.472 us; speedup 1.0000x reference)
//
#include <hip/hip_runtime.h>
#include <hip/hip_bf16.h>

// Problem constants
#define NPTS   65536
#define CCH    384
#define NH     6
#define DH     64
#define KP     256   // patch size
#define NPATCH 256   // NPTS / KP
#define PB     20    // POS_BND
#define RNUM   41    // 2*PB+1
#define K1     384   // GEMM inner dim

typedef float f32x4 __attribute__((ext_vector_type(4)));
typedef short s16x8 __attribute__((ext_vector_type(8)));
typedef short s16x4 __attribute__((ext_vector_type(4)));
typedef unsigned u32x4 __attribute__((ext_vector_type(4)));
typedef unsigned short u16;
typedef u16 u16x4 __attribute__((ext_vector_type(4)));

static __device__ __forceinline__ u16 f2b(float f) {
    union { __hip_bfloat16 h; u16 u; } cv;
    cv.h = __float2bfloat16(f);
    return cv.u;
}
static __device__ __forceinline__ float b2f(u16 u) {
    union { float f; unsigned v; } cv; cv.v = ((unsigned)u) << 16; return cv.f;
}
static __device__ __forceinline__ void split1(float x, u16& h, u16& l) {
    h = f2b(x);
    l = f2b(x - b2f(h));
}
// packed bf16 convert: dst = {lo: cvt(a), hi: cvt(b)} (RNE, m214v22-verified)
static __device__ __forceinline__ unsigned cvtpk(float a, float b) {
    unsigned r;
    asm("v_cvt_pk_bf16_f32 %0, %1, %2" : "=v"(r) : "v"(a), "v"(b));
    return r;
}

typedef __attribute__((address_space(3))) unsigned lds_u;
typedef const __attribute__((address_space(1))) unsigned glob_u;
static __device__ __forceinline__ void gll16(const void* g, void* l) {
    __builtin_amdgcn_global_load_lds((glob_u*)g, (lds_u*)l, 16, 0, 0);
}

// ---------------------------------------------------------------------------
// Prep kernels
// ---------------------------------------------------------------------------
__global__ __launch_bounds__(256) void split_arr(
    const float* __restrict__ s, u16* __restrict__ h, u16* __restrict__ l, int n4)
{
    int i = blockIdx.x * 256 + threadIdx.x;
    if (i >= n4) return;
    float4 v = ((const float4*)s)[i];
    u16 h0, l0, h1, l1, h2, l2, h3, l3;
    split1(v.x, h0, l0); split1(v.y, h1, l1);
    split1(v.z, h2, l2); split1(v.w, h3, l3);
    u16x4 hv, lv;
    hv[0] = h0; hv[1] = h1; hv[2] = h2; hv[3] = h3;
    lv[0] = l0; lv[1] = l1; lv[2] = l2; lv[3] = l3;
    *(u16x4*)&h[(size_t)i * 4] = hv;
    *(u16x4*)&l[(size_t)i * 4] = lv;
}

__global__ __launch_bounds__(256) void cast_bf16(
    const float* __restrict__ s, u16* __restrict__ d, int n4)
{
    int i = blockIdx.x * 256 + threadIdx.x;
    if (i >= n4) return;
    float4 v = ((const float4*)s)[i];
    u16x4 hv;
    hv[0] = f2b(v.x); hv[1] = f2b(v.y); hv[2] = f2b(v.z); hv[3] = f2b(v.w);
    *(u16x4*)&d[(size_t)i * 4] = hv;
}

// Gather fh = bf16(feat[order[j]])
__global__ __launch_bounds__(256) void gather_h(
    const float* __restrict__ feat, const int* __restrict__ order,
    u16* __restrict__ fh)
{
    int i = blockIdx.x * 256 + threadIdx.x;   // over NPTS*96 float4s
    int r = i / 96, c4 = i % 96;
    int o = order[r];
    float4 v = *((const float4*)(feat + (size_t)o * CCH) + c4);
    u16x4 hv;
    hv[0] = f2b(v.x); hv[1] = f2b(v.y); hv[2] = f2b(v.z); hv[3] = f2b(v.w);
    *(u16x4*)&fh[(size_t)r * CCH + c4 * 4] = hv;
}

__global__ __launch_bounds__(256) void pack_coords(
    const int* __restrict__ order, const int* __restrict__ gcoord,
    unsigned* __restrict__ cpk_g)
{
    int j = blockIdx.x * 256 + threadIdx.x;
    int o = order[j];
    const int* gc = gcoord + (size_t)o * 3;
    cpk_g[j] = (unsigned)gc[0] | ((unsigned)gc[1] << 10) | ((unsigned)gc[2] << 20);
}

// ---------------------------------------------------------------------------
// Kernel A: 1-term bf16 GEMM (qkv): C = Ah*Bh   (frozen from R18)
// ---------------------------------------------------------------------------
__global__ __launch_bounds__(256, 4) void gemm_qkv(
    const u16* __restrict__ Ah, const u16* __restrict__ Bh,
    const float* __restrict__ bias,
    u16* __restrict__ q_out, u16* __restrict__ k_out, u16* __restrict__ vt_out)
{
    __shared__ __align__(16) u16 lds[2 * 128 * 64];   // 32 KB
    u16* LAh = lds;
    u16* LBh = lds + 128 * 64;

    const int t = threadIdx.x;
    const int lane = t & 63, wv = t >> 6;
    const int L = lane & 15, gq = lane >> 4;
    const int wr = wv >> 1, wc = wv & 1;

    const int orig = blockIdx.y * 9 + blockIdx.x;
    const int swz  = (orig & 7) * 576 + (orig >> 3);        // bijective (4608%8==0)
    const int n0 = (swz % 9) * 128;
    const int m0 = (swz / 9) * 128;

    f32x4 acc[4][4];
#pragma unroll
    for (int mi = 0; mi < 4; ++mi)
#pragma unroll
        for (int ni = 0; ni < 4; ++ni) acc[mi][ni] = (f32x4)0.f;

    for (int kc = 0; kc < K1; kc += 64) {
        __syncthreads();
#pragma unroll
        for (int i = 0; i < 4; ++i) {
            int ci = i * 256 + t;
            int r = ci >> 3, j = ci & 7;
            int c8 = (j ^ (r & 7)) * 8;
            gll16(Ah + (size_t)(m0 + r) * K1 + kc + c8, LAh + ci * 8);
            gll16(Bh + (size_t)(n0 + r) * K1 + kc + c8, LBh + ci * 8);
        }
        __syncthreads();
#pragma unroll
        for (int ks = 0; ks < 2; ++ks) {
            s16x8 fah[4], fbh[4];
#pragma unroll
            for (int x = 0; x < 4; ++x) {
                int arow = wr * 64 + x * 16 + L;
                int brow = wc * 64 + x * 16 + L;
                int ka  = ((ks * 4 + gq) ^ (arow & 7)) * 8;
                int kb2 = ((ks * 4 + gq) ^ (brow & 7)) * 8;
                fah[x] = *(const s16x8*)&LAh[arow * 64 + ka];
                fbh[x] = *(const s16x8*)&LBh[brow * 64 + kb2];
            }
#pragma unroll
            for (int mi = 0; mi < 4; ++mi)
#pragma unroll
                for (int ni = 0; ni < 4; ++ni)
                    acc[mi][ni] = __builtin_amdgcn_mfma_f32_16x16x32_bf16(
                        fah[mi], fbh[ni], acc[mi][ni], 0, 0, 0);
        }
    }

    float bfrag[4];
#pragma unroll
    for (int ni = 0; ni < 4; ++ni) bfrag[ni] = bias[n0 + wc * 64 + ni * 16 + L];

    const int cq   = n0 + wc * 64;
    const int ssel = cq / CCH;
    const int hh   = (cq % CCH) / DH;

    if (ssel == 2) {
#pragma unroll
        for (int mi = 0; mi < 4; ++mi) {
            int jb = m0 + wr * 64 + mi * 16;
            int p = jb >> 8, kr0 = (jb & 255) + gq * 4;
            size_t hb = (size_t)(p * NH + hh) * DH;
#pragma unroll
            for (int ni = 0; ni < 4; ++ni) {
                int d = ni * 16 + L;
                u16x4 w;
#pragma unroll
                for (int reg = 0; reg < 4; ++reg)
                    w[reg] = f2b(acc[mi][ni][reg] + bfrag[ni]);
                int kswz = (kr0 & ~63) + ((kr0 & 63) ^ ((d & 7) << 3));
                *(u16x4*)&vt_out[(hb + d) * KP + kswz] = w;
            }
        }
    } else if (ssel == 1) {
#pragma unroll
        for (int mi = 0; mi < 4; ++mi)
#pragma unroll
            for (int reg = 0; reg < 4; ++reg) {
                int j = m0 + wr * 64 + mi * 16 + gq * 4 + reg;
                int kk = j & 255;
                u16* orow = k_out + ((size_t)((j >> 8) * NH + hh) * KP + kk) * DH;
                int sw = (kk & 7) << 3;
#pragma unroll
                for (int ni = 0; ni < 4; ++ni)
                    orow[(ni * 16 + L) ^ sw] = f2b(acc[mi][ni][reg] + bfrag[ni]);
            }
    } else {
#pragma unroll
        for (int mi = 0; mi < 4; ++mi)
#pragma unroll
            for (int reg = 0; reg < 4; ++reg) {
                int j = m0 + wr * 64 + mi * 16 + gq * 4 + reg;
                u16* orow = q_out + ((size_t)((j >> 8) * NH + hh) * KP + (j & 255)) * DH;
#pragma unroll
                for (int ni = 0; ni < 4; ++ni)
                    orow[ni * 16 + L] = f2b((acc[mi][ni][reg] + bfrag[ni]) * 0.125f);
            }
    }
}

// ---------------------------------------------------------------------------
// Kernel B: swapped-operand MFMA flash attention per (patch, head).
// VALU-trimmed: combined 41x41 x+y RPE table (1 ds_read + 1 add saved per
// element) and v_cvt_pk_bf16_f32 P-pack (replaces 8 slow f2b per ki).
// ---------------------------------------------------------------------------
#define LDSK  0
#define LDSV  8192
#define CPKO  16384
#define RPEXY 17408                 // 1681 f32 = 6724 B
#define RPEZ  24132                 // 41 f32
#define SMEMSZ 24320

__global__ __launch_bounds__(512, 4) void attn_mfma(
    const u16* __restrict__ q_s, const u16* __restrict__ k_s,
    const u16* __restrict__ vt_s, const unsigned* __restrict__ cpk_g,
    const float* __restrict__ rpe_table, u16* __restrict__ oa16)
{
    __shared__ __align__(16) unsigned char smem[SMEMSZ];
    unsigned* cpk   = (unsigned*)&smem[CPKO];
    float*    rpexy = (float*)&smem[RPEXY];
    float*    rpez  = (float*)&smem[RPEZ];

    const int t    = threadIdx.x;
    const int p    = blockIdx.x, h = blockIdx.y;
    const int lane = t & 63, wv = t >> 6;
    const int L    = lane & 15, gq = lane >> 4;
    const int q0   = wv * 32;
    const size_t base = (size_t)(p * NH + h) * KP * DH;

    if (t < KP) cpk[t] = cpk_g[p * KP + t];
    // build combined x+y table and z table
    for (int idx = t; idx < RNUM * RNUM; idx += 512) {
        int ix = idx % RNUM, iy = idx / RNUM;
        rpexy[idx] = rpe_table[ix * NH + h] + rpe_table[(RNUM + iy) * NH + h];
    }
    if (t < RNUM) rpez[t] = rpe_table[(2 * RNUM + t) * NH + h];
    __syncthreads();

    // q coords, +PB folded (index base): qb = q + 20
    int qxb[2], qyb[2], qzb[2];
#pragma unroll
    for (int qi = 0; qi < 2; ++qi) {
        unsigned c = cpk[q0 + qi * 16 + L];
        qxb[qi] = (int)(c & 1023u) + PB;
        qyb[qi] = (int)((c >> 10) & 1023u) + PB;
        qzb[qi] = (int)(c >> 20) + PB;
    }

    s16x8 aq[2][2];
#pragma unroll
    for (int qi = 0; qi < 2; ++qi)
#pragma unroll
        for (int ks = 0; ks < 2; ++ks)
            aq[qi][ks] = *(const s16x8*)&q_s[base +
                (size_t)(q0 + qi * 16 + L) * DH + ks * 32 + gq * 8];

    f32x4 oacc[2][4];
#pragma unroll
    for (int qi = 0; qi < 2; ++qi)
#pragma unroll
        for (int nd = 0; nd < 4; ++nd) oacc[qi][nd] = (f32x4)0.f;
    float lsum[2] = {0.f, 0.f};

    const int srow = t >> 3;
    const int sc8  = (t & 7) * 8;

    for (int kb = 0; kb < 4; ++kb) {
        __syncthreads();
        {
            const u16* kg = k_s + base + (size_t)(kb * 64 + srow) * DH + sc8;
            gll16(kg, &smem[LDSK + t * 16]);
            const u16* vg = vt_s + base + (size_t)srow * KP + kb * 64 + sc8;
            gll16(vg, &smem[LDSV + t * 16]);
        }
        __syncthreads();

#pragma unroll
        for (int ki = 0; ki < 4; ++ki) {
            const int krow = ki * 16 + L;
            const int kxor = (krow & 7) << 4;
            s16x8 ak0 = *(const s16x8*)&smem[LDSK + krow * 128 + ((gq * 16) ^ kxor)];
            s16x8 ak1 = *(const s16x8*)&smem[LDSK + krow * 128 + ((64 + gq * 16) ^ kxor)];

            f32x4 sacc[2];
            __builtin_amdgcn_s_setprio(1);
#pragma unroll
            for (int qi = 0; qi < 2; ++qi) {
                sacc[qi] = __builtin_amdgcn_mfma_f32_16x16x32_bf16(
                    ak0, aq[qi][0], (f32x4)0.f, 0, 0, 0);
                sacc[qi] = __builtin_amdgcn_mfma_f32_16x16x32_bf16(
                    ak1, aq[qi][1], sacc[qi], 0, 0, 0);
            }
            __builtin_amdgcn_s_setprio(0);

            u32x4 ck4 = *(const u32x4*)&cpk[kb * 64 + ki * 16 + gq * 4];
            int kx[4], ky[4], kz[4];
#pragma unroll
            for (int j = 0; j < 4; ++j) {
                unsigned c = ck4[j];
                kx[j] = (int)(c & 1023u);
                ky[j] = (int)((c >> 10) & 1023u);
                kz[j] = (int)(c >> 20);
            }

            s16x4 pf[2];
#pragma unroll
            for (int qi = 0; qi < 2; ++qi) {
                float pe[4];
#pragma unroll
                for (int j = 0; j < 4; ++j) {
                    int ix = qxb[qi] - kx[j]; ix = ix < 0 ? 0 : (ix > 40 ? 40 : ix);
                    int iy = qyb[qi] - ky[j]; iy = iy < 0 ? 0 : (iy > 40 ? 40 : iy);
                    int iz = qzb[qi] - kz[j]; iz = iz < 0 ? 0 : (iz > 40 ? 40 : iz);
                    float sv = sacc[qi][j] + rpexy[iy * RNUM + ix] + rpez[iz];
                    pe[j] = __expf(sv);
                    lsum[qi] += pe[j];
                }
                union { unsigned w[2]; s16x4 v; } u;
                u.w[0] = cvtpk(pe[0], pe[1]);
                u.w[1] = cvtpk(pe[2], pe[3]);
                pf[qi] = u.v;
            }

            __builtin_amdgcn_s_setprio(1);
#pragma unroll
            for (int nd = 0; nd < 4; ++nd) {
                int d = nd * 16 + L;
                s16x4 vf = *(const s16x4*)&smem[LDSV + d * 128 +
                    (((ki * 16 + gq * 4) * 2) ^ ((d & 7) << 4))];
#pragma unroll
                for (int qi = 0; qi < 2; ++qi)
                    oacc[qi][nd] = __builtin_amdgcn_mfma_f32_16x16x16bf16_1k(
                        pf[qi], vf, oacc[qi][nd], 0, 0, 0);
            }
            __builtin_amdgcn_s_setprio(0);
        }
    }

    float linv[2];
#pragma unroll
    for (int qi = 0; qi < 2; ++qi) {
        float l2 = lsum[qi];
        l2 += __shfl_xor(l2, 16);
        l2 += __shfl_xor(l2, 32);
        linv[qi] = 1.f / l2;
    }

    // staging + tables dead; per-wave [16][72] u16 transpose buffer
    __syncthreads();
    u16* ot = (u16*)&smem[wv * 2304];
#pragma unroll
    for (int qi = 0; qi < 2; ++qi) {
#pragma unroll
        for (int reg = 0; reg < 4; ++reg) {
            float li = __shfl(linv[qi], gq * 4 + reg);
#pragma unroll
            for (int nd = 0; nd < 4; ++nd)
                ot[(gq * 4 + reg) * 72 + nd * 16 + L] = f2b(oacc[qi][nd][reg] * li);
        }
#pragma unroll
        for (int s = 0; s < 4; ++s) {
            int r = s * 4 + (lane >> 4);
            int c = (lane & 15) * 4;
            u16x4 a = *(const u16x4*)&ot[r * 72 + c];
            int q = q0 + qi * 16 + r;
            *(u16x4*)&oa16[(size_t)(p * KP + q) * CCH + h * DH + c] = a;
        }
    }
}

// ---------------------------------------------------------------------------
// Kernel C: proj GEMM: out = A16 @ (Bh+Bl)^T + bias  (frozen from R18)
// ---------------------------------------------------------------------------
__global__ __launch_bounds__(256, 3) void gemm_proj(
    const u16* __restrict__ A16,
    const u16* __restrict__ Bh, const u16* __restrict__ Bl,
    const float* __restrict__ bias, const int* __restrict__ order,
    float* __restrict__ out)
{
    __shared__ __align__(16) unsigned char smemP[49152];   // 48 KB
    u16* LA  = (u16*)smemP;
    u16* LBh = (u16*)&smemP[16384];
    u16* LBl = (u16*)&smemP[32768];

    const int t = threadIdx.x;
    const int lane = t & 63, wv = t >> 6;
    const int L = lane & 15, gq = lane >> 4;
    const int wr = wv >> 1, wc = wv & 1;

    const int orig = blockIdx.y * 3 + blockIdx.x;
    const int swz  = (orig & 7) * 192 + (orig >> 3);        // bijective (1536%8==0)
    const int n0 = (swz % 3) * 128;
    const int m0 = (swz / 3) * 128;

    f32x4 acc[4][4];
#pragma unroll
    for (int mi = 0; mi < 4; ++mi)
#pragma unroll
        for (int ni = 0; ni < 4; ++ni) acc[mi][ni] = (f32x4)0.f;

    for (int kc = 0; kc < K1; kc += 64) {
        __syncthreads();
#pragma unroll
        for (int i = 0; i < 4; ++i) {
            int ci = i * 256 + t;
            int r = ci >> 3, j = ci & 7;
            int c8 = (j ^ (r & 7)) * 8;
            gll16(A16 + (size_t)(m0 + r) * K1 + kc + c8, LA + ci * 8);
            size_t gb = (size_t)(n0 + r) * K1 + kc + c8;
            gll16(Bh + gb, LBh + ci * 8);
            gll16(Bl + gb, LBl + ci * 8);
        }
        __syncthreads();
#pragma unroll
        for (int ks = 0; ks < 2; ++ks) {
            s16x8 fah[4], fbh[4], fbl[4];
#pragma unroll
            for (int x = 0; x < 4; ++x) {
                int arow = wr * 64 + x * 16 + L;
                int brow = wc * 64 + x * 16 + L;
                int ka  = ((ks * 4 + gq) ^ (arow & 7)) * 8;
                int kb2 = ((ks * 4 + gq) ^ (brow & 7)) * 8;
                fah[x] = *(const s16x8*)&LA[arow * 64 + ka];
                fbh[x] = *(const s16x8*)&LBh[brow * 64 + kb2];
                fbl[x] = *(const s16x8*)&LBl[brow * 64 + kb2];
            }
#pragma unroll
            for (int mi = 0; mi < 4; ++mi)
#pragma unroll
                for (int ni = 0; ni < 4; ++ni) {
                    acc[mi][ni] = __builtin_amdgcn_mfma_f32_16x16x32_bf16(
                        fah[mi], fbh[ni], acc[mi][ni], 0, 0, 0);
                    acc[mi][ni] = __builtin_amdgcn_mfma_f32_16x16x32_bf16(
                        fah[mi], fbl[ni], acc[mi][ni], 0, 0, 0);
                }
        }
    }

    float bfrag[4];
#pragma unroll
    for (int ni = 0; ni < 4; ++ni) bfrag[ni] = bias[n0 + wc * 64 + ni * 16 + L];

    __syncthreads();
    float* otp = (float*)smemP + wv * 1088;   // [16][68] f32 per wave
#pragma unroll
    for (int mi = 0; mi < 4; ++mi) {
#pragma unroll
        for (int reg = 0; reg < 4; ++reg)
#pragma unroll
            for (int ni = 0; ni < 4; ++ni)
                otp[(gq * 4 + reg) * 68 + ni * 16 + L] = acc[mi][ni][reg] + bfrag[ni];
#pragma unroll
        for (int s = 0; s < 4; ++s) {
            int r = s * 4 + (lane >> 4);
            int c = (lane & 15) * 4;
            f32x4 a = *(const f32x4*)&otp[r * 68 + c];
            int j = m0 + wr * 64 + mi * 16 + r;
            float* dst = out + (size_t)order[j] * CCH + n0 + wc * 64 + c;
            *(f32x4*)dst = a;
        }
        __syncthreads();
    }
}

// ---------------------------------------------------------------------------
extern "C" void kernel_launch(void* const* d_in, const int* in_sizes, int n_in,
                              void* d_out, int out_size, void* d_ws, size_t ws_size,
                              hipStream_t stream) {
    const float* feat      = (const float*)d_in[0];
    const float* qkv_w     = (const float*)d_in[1];
    const float* qkv_b     = (const float*)d_in[2];
    const float* proj_w    = (const float*)d_in[3];
    const float* proj_b    = (const float*)d_in[4];
    const float* rpe_table = (const float*)d_in[5];
    const int*   order     = (const int*)d_in[6];
    const int*   gcoord    = (const int*)d_in[8];
    float* out = (float*)d_out;

    const size_t NC = (size_t)NPTS * CCH;
    u16* fh   = (u16*)d_ws;
    u16* qwh  = fh + NC;
    u16* pwh  = qwh + (size_t)1152 * 384;
    u16* pwl  = pwh + (size_t)384 * 384;
    u16* qs   = pwl + (size_t)384 * 384;
    u16* ks   = qs + NC;
    u16* vts  = ks + NC;
    u16* oa16 = vts + NC;
    unsigned* cpk_g = (unsigned*)(oa16 + NC);

    cast_bf16<<<(1152 * 384 / 4 + 255) / 256, 256, 0, stream>>>(qkv_w, qwh, 1152 * 384 / 4);
    split_arr<<<(384 * 384 / 4 + 255) / 256, 256, 0, stream>>>(proj_w, pwh, pwl, 384 * 384 / 4);
    gather_h<<<NPTS * 96 / 256, 256, 0, stream>>>(feat, order, fh);
    pack_coords<<<NPTS / 256, 256, 0, stream>>>(order, gcoord, cpk_g);

    gemm_qkv<<<dim3(9, NPTS / 128), 256, 0, stream>>>(
        fh, qwh, qkv_b, qs, ks, vts);
    attn_mfma<<<dim3(NPATCH, NH), 512, 0, stream>>>(
        qs, ks, vts, cpk_g, rpe_table, oa16);
    gemm_proj<<<dim3(3, NPTS / 128), 256, 0, stream>>>(
        oa16, pwh, pwl, proj_b, order, out);
}

// Round 21
// 237.547 us; speedup vs baseline: 1.0081x; 1.0081x over previous
//
#include <hip/hip_runtime.h>
#include <hip/hip_bf16.h>

// Problem constants
#define NPTS   65536
#define CCH    384
#define NH     6
#define DH     64
#define KP     256   // patch size
#define NPATCH 256   // NPTS / KP
#define PB     20    // POS_BND
#define RNUM   41    // 2*PB+1
#define K1     384   // GEMM inner dim
#define LOG2E  1.44269504088896f

typedef float f32x4 __attribute__((ext_vector_type(4)));
typedef short s16x8 __attribute__((ext_vector_type(8)));
typedef short s16x4 __attribute__((ext_vector_type(4)));
typedef unsigned u32x4 __attribute__((ext_vector_type(4)));
typedef unsigned short u16;
typedef u16 u16x4 __attribute__((ext_vector_type(4)));

static __device__ __forceinline__ u16 f2b(float f) {
    union { __hip_bfloat16 h; u16 u; } cv;
    cv.h = __float2bfloat16(f);
    return cv.u;
}
static __device__ __forceinline__ float b2f(u16 u) {
    union { float f; unsigned v; } cv; cv.v = ((unsigned)u) << 16; return cv.f;
}
static __device__ __forceinline__ void split1(float x, u16& h, u16& l) {
    h = f2b(x);
    l = f2b(x - b2f(h));
}
// packed bf16 convert: dst = {lo: cvt(a), hi: cvt(b)} (RNE)
static __device__ __forceinline__ unsigned cvtpk(float a, float b) {
    unsigned r;
    asm("v_cvt_pk_bf16_f32 %0, %1, %2" : "=v"(r) : "v"(a), "v"(b));
    return r;
}
// raw v_exp_f32 = exp2
static __device__ __forceinline__ float exp2r(float x) {
    float r;
    asm("v_exp_f32 %0, %1" : "=v"(r) : "v"(x));
    return r;
}

typedef __attribute__((address_space(3))) unsigned lds_u;
typedef const __attribute__((address_space(1))) unsigned glob_u;
static __device__ __forceinline__ void gll16(const void* g, void* l) {
    __builtin_amdgcn_global_load_lds((glob_u*)g, (lds_u*)l, 16, 0, 0);
}

// ---------------------------------------------------------------------------
// Prep kernels
// ---------------------------------------------------------------------------
__global__ __launch_bounds__(256) void split_arr(
    const float* __restrict__ s, u16* __restrict__ h, u16* __restrict__ l, int n4)
{
    int i = blockIdx.x * 256 + threadIdx.x;
    if (i >= n4) return;
    float4 v = ((const float4*)s)[i];
    u16 h0, l0, h1, l1, h2, l2, h3, l3;
    split1(v.x, h0, l0); split1(v.y, h1, l1);
    split1(v.z, h2, l2); split1(v.w, h3, l3);
    u16x4 hv, lv;
    hv[0] = h0; hv[1] = h1; hv[2] = h2; hv[3] = h3;
    lv[0] = l0; lv[1] = l1; lv[2] = l2; lv[3] = l3;
    *(u16x4*)&h[(size_t)i * 4] = hv;
    *(u16x4*)&l[(size_t)i * 4] = lv;
}

__global__ __launch_bounds__(256) void cast_bf16(
    const float* __restrict__ s, u16* __restrict__ d, int n4)
{
    int i = blockIdx.x * 256 + threadIdx.x;
    if (i >= n4) return;
    float4 v = ((const float4*)s)[i];
    u16x4 hv;
    hv[0] = f2b(v.x); hv[1] = f2b(v.y); hv[2] = f2b(v.z); hv[3] = f2b(v.w);
    *(u16x4*)&d[(size_t)i * 4] = hv;
}

// Gather fh = bf16(feat[order[j]])
__global__ __launch_bounds__(256) void gather_h(
    const float* __restrict__ feat, const int* __restrict__ order,
    u16* __restrict__ fh)
{
    int i = blockIdx.x * 256 + threadIdx.x;   // over NPTS*96 float4s
    int r = i / 96, c4 = i % 96;
    int o = order[r];
    float4 v = *((const float4*)(feat + (size_t)o * CCH) + c4);
    u16x4 hv;
    hv[0] = f2b(v.x); hv[1] = f2b(v.y); hv[2] = f2b(v.z); hv[3] = f2b(v.w);
    *(u16x4*)&fh[(size_t)r * CCH + c4 * 4] = hv;
}

__global__ __launch_bounds__(256) void pack_coords(
    const int* __restrict__ order, const int* __restrict__ gcoord,
    unsigned* __restrict__ cpk_g)
{
    int j = blockIdx.x * 256 + threadIdx.x;
    int o = order[j];
    const int* gc = gcoord + (size_t)o * 3;
    cpk_g[j] = (unsigned)gc[0] | ((unsigned)gc[1] << 10) | ((unsigned)gc[2] << 20);
}

// ---------------------------------------------------------------------------
// Kernel A: 1-term bf16 GEMM (qkv): C = Ah*Bh
// Q epilogue scale now 0.125*log2(e) (attn uses exp2 directly).
// ---------------------------------------------------------------------------
__global__ __launch_bounds__(256, 4) void gemm_qkv(
    const u16* __restrict__ Ah, const u16* __restrict__ Bh,
    const float* __restrict__ bias,
    u16* __restrict__ q_out, u16* __restrict__ k_out, u16* __restrict__ vt_out)
{
    __shared__ __align__(16) u16 lds[2 * 128 * 64];   // 32 KB
    u16* LAh = lds;
    u16* LBh = lds + 128 * 64;

    const int t = threadIdx.x;
    const int lane = t & 63, wv = t >> 6;
    const int L = lane & 15, gq = lane >> 4;
    const int wr = wv >> 1, wc = wv & 1;

    const int orig = blockIdx.y * 9 + blockIdx.x;
    const int swz  = (orig & 7) * 576 + (orig >> 3);        // bijective (4608%8==0)
    const int n0 = (swz % 9) * 128;
    const int m0 = (swz / 9) * 128;

    f32x4 acc[4][4];
#pragma unroll
    for (int mi = 0; mi < 4; ++mi)
#pragma unroll
        for (int ni = 0; ni < 4; ++ni) acc[mi][ni] = (f32x4)0.f;

    for (int kc = 0; kc < K1; kc += 64) {
        __syncthreads();
#pragma unroll
        for (int i = 0; i < 4; ++i) {
            int ci = i * 256 + t;
            int r = ci >> 3, j = ci & 7;
            int c8 = (j ^ (r & 7)) * 8;
            gll16(Ah + (size_t)(m0 + r) * K1 + kc + c8, LAh + ci * 8);
            gll16(Bh + (size_t)(n0 + r) * K1 + kc + c8, LBh + ci * 8);
        }
        __syncthreads();
#pragma unroll
        for (int ks = 0; ks < 2; ++ks) {
            s16x8 fah[4], fbh[4];
#pragma unroll
            for (int x = 0; x < 4; ++x) {
                int arow = wr * 64 + x * 16 + L;
                int brow = wc * 64 + x * 16 + L;
                int ka  = ((ks * 4 + gq) ^ (arow & 7)) * 8;
                int kb2 = ((ks * 4 + gq) ^ (brow & 7)) * 8;
                fah[x] = *(const s16x8*)&LAh[arow * 64 + ka];
                fbh[x] = *(const s16x8*)&LBh[brow * 64 + kb2];
            }
#pragma unroll
            for (int mi = 0; mi < 4; ++mi)
#pragma unroll
                for (int ni = 0; ni < 4; ++ni)
                    acc[mi][ni] = __builtin_amdgcn_mfma_f32_16x16x32_bf16(
                        fah[mi], fbh[ni], acc[mi][ni], 0, 0, 0);
        }
    }

    float bfrag[4];
#pragma unroll
    for (int ni = 0; ni < 4; ++ni) bfrag[ni] = bias[n0 + wc * 64 + ni * 16 + L];

    const int cq   = n0 + wc * 64;
    const int ssel = cq / CCH;
    const int hh   = (cq % CCH) / DH;

    if (ssel == 2) {
#pragma unroll
        for (int mi = 0; mi < 4; ++mi) {
            int jb = m0 + wr * 64 + mi * 16;
            int p = jb >> 8, kr0 = (jb & 255) + gq * 4;
            size_t hb = (size_t)(p * NH + hh) * DH;
#pragma unroll
            for (int ni = 0; ni < 4; ++ni) {
                int d = ni * 16 + L;
                u16x4 w;
#pragma unroll
                for (int reg = 0; reg < 4; ++reg)
                    w[reg] = f2b(acc[mi][ni][reg] + bfrag[ni]);
                int kswz = (kr0 & ~63) + ((kr0 & 63) ^ ((d & 7) << 3));
                *(u16x4*)&vt_out[(hb + d) * KP + kswz] = w;
            }
        }
    } else if (ssel == 1) {
#pragma unroll
        for (int mi = 0; mi < 4; ++mi)
#pragma unroll
            for (int reg = 0; reg < 4; ++reg) {
                int j = m0 + wr * 64 + mi * 16 + gq * 4 + reg;
                int kk = j & 255;
                u16* orow = k_out + ((size_t)((j >> 8) * NH + hh) * KP + kk) * DH;
                int sw = (kk & 7) << 3;
#pragma unroll
                for (int ni = 0; ni < 4; ++ni)
                    orow[(ni * 16 + L) ^ sw] = f2b(acc[mi][ni][reg] + bfrag[ni]);
            }
    } else {
        const float qscl = 0.125f * LOG2E;
#pragma unroll
        for (int mi = 0; mi < 4; ++mi)
#pragma unroll
            for (int reg = 0; reg < 4; ++reg) {
                int j = m0 + wr * 64 + mi * 16 + gq * 4 + reg;
                u16* orow = q_out + ((size_t)((j >> 8) * NH + hh) * KP + (j & 255)) * DH;
#pragma unroll
                for (int ni = 0; ni < 4; ++ni)
                    orow[ni * 16 + L] = f2b((acc[mi][ni][reg] + bfrag[ni]) * qscl);
            }
    }
}

// ---------------------------------------------------------------------------
// Kernel B: swapped-operand MFMA flash attention per (patch, head).
// exp2-domain softmax (tables pre-scaled by log2e); row-sum l computed on
// the MATRIX pipe via a ones-column MFMA (lane-local, no shuffle reduce).
// ---------------------------------------------------------------------------
#define LDSK  0
#define LDSV  8192
#define CPKO  16384
#define RPEXY 17408                 // 1681 f32 = 6724 B
#define RPEZ  24132                 // 41 f32
#define SMEMSZ 24320

__global__ __launch_bounds__(512, 4) void attn_mfma(
    const u16* __restrict__ q_s, const u16* __restrict__ k_s,
    const u16* __restrict__ vt_s, const unsigned* __restrict__ cpk_g,
    const float* __restrict__ rpe_table, u16* __restrict__ oa16)
{
    __shared__ __align__(16) unsigned char smem[SMEMSZ];
    unsigned* cpk   = (unsigned*)&smem[CPKO];
    float*    rpexy = (float*)&smem[RPEXY];
    float*    rpez  = (float*)&smem[RPEZ];

    const int t    = threadIdx.x;
    const int p    = blockIdx.x, h = blockIdx.y;
    const int lane = t & 63, wv = t >> 6;
    const int L    = lane & 15, gq = lane >> 4;
    const int q0   = wv * 32;
    const size_t base = (size_t)(p * NH + h) * KP * DH;

    if (t < KP) cpk[t] = cpk_g[p * KP + t];
    // combined x+y table and z table, pre-scaled by log2(e) for exp2 domain
    for (int idx = t; idx < RNUM * RNUM; idx += 512) {
        int ix = idx % RNUM, iy = idx / RNUM;
        rpexy[idx] = (rpe_table[ix * NH + h] + rpe_table[(RNUM + iy) * NH + h]) * LOG2E;
    }
    if (t < RNUM) rpez[t] = rpe_table[(2 * RNUM + t) * NH + h] * LOG2E;
    __syncthreads();

    int qxb[2], qyb[2], qzb[2];
#pragma unroll
    for (int qi = 0; qi < 2; ++qi) {
        unsigned c = cpk[q0 + qi * 16 + L];
        qxb[qi] = (int)(c & 1023u) + PB;
        qyb[qi] = (int)((c >> 10) & 1023u) + PB;
        qzb[qi] = (int)(c >> 20) + PB;
    }

    s16x8 aq[2][2];
#pragma unroll
    for (int qi = 0; qi < 2; ++qi)
#pragma unroll
        for (int ks = 0; ks < 2; ++ks)
            aq[qi][ks] = *(const s16x8*)&q_s[base +
                (size_t)(q0 + qi * 16 + L) * DH + ks * 32 + gq * 8];

    f32x4 oacc[2][4];
    f32x4 lacc[2];
#pragma unroll
    for (int qi = 0; qi < 2; ++qi) {
#pragma unroll
        for (int nd = 0; nd < 4; ++nd) oacc[qi][nd] = (f32x4)0.f;
        lacc[qi] = (f32x4)0.f;
    }
    // bf16 1.0 fragment for the ones-column row-sum MFMA
    s16x4 vone;
    vone[0] = (short)0x3F80; vone[1] = (short)0x3F80;
    vone[2] = (short)0x3F80; vone[3] = (short)0x3F80;

    const int srow = t >> 3;
    const int sc8  = (t & 7) * 8;

    for (int kb = 0; kb < 4; ++kb) {
        __syncthreads();
        {
            const u16* kg = k_s + base + (size_t)(kb * 64 + srow) * DH + sc8;
            gll16(kg, &smem[LDSK + t * 16]);
            const u16* vg = vt_s + base + (size_t)srow * KP + kb * 64 + sc8;
            gll16(vg, &smem[LDSV + t * 16]);
        }
        __syncthreads();

#pragma unroll
        for (int ki = 0; ki < 4; ++ki) {
            const int krow = ki * 16 + L;
            const int kxor = (krow & 7) << 4;
            s16x8 ak0 = *(const s16x8*)&smem[LDSK + krow * 128 + ((gq * 16) ^ kxor)];
            s16x8 ak1 = *(const s16x8*)&smem[LDSK + krow * 128 + ((64 + gq * 16) ^ kxor)];

            f32x4 sacc[2];
            __builtin_amdgcn_s_setprio(1);
#pragma unroll
            for (int qi = 0; qi < 2; ++qi) {
                sacc[qi] = __builtin_amdgcn_mfma_f32_16x16x32_bf16(
                    ak0, aq[qi][0], (f32x4)0.f, 0, 0, 0);
                sacc[qi] = __builtin_amdgcn_mfma_f32_16x16x32_bf16(
                    ak1, aq[qi][1], sacc[qi], 0, 0, 0);
            }
            __builtin_amdgcn_s_setprio(0);

            u32x4 ck4 = *(const u32x4*)&cpk[kb * 64 + ki * 16 + gq * 4];
            int kx[4], ky[4], kz[4];
#pragma unroll
            for (int j = 0; j < 4; ++j) {
                unsigned c = ck4[j];
                kx[j] = (int)(c & 1023u);
                ky[j] = (int)((c >> 10) & 1023u);
                kz[j] = (int)(c >> 20);
            }

            s16x4 pf[2];
#pragma unroll
            for (int qi = 0; qi < 2; ++qi) {
                float pe[4];
#pragma unroll
                for (int j = 0; j < 4; ++j) {
                    int ix = qxb[qi] - kx[j]; ix = ix < 0 ? 0 : (ix > 40 ? 40 : ix);
                    int iy = qyb[qi] - ky[j]; iy = iy < 0 ? 0 : (iy > 40 ? 40 : iy);
                    int iz = qzb[qi] - kz[j]; iz = iz < 0 ? 0 : (iz > 40 ? 40 : iz);
                    float sv = sacc[qi][j] + rpexy[iy * RNUM + ix] + rpez[iz];
                    pe[j] = exp2r(sv);
                }
                union { unsigned w[2]; s16x4 v; } u;
                u.w[0] = cvtpk(pe[0], pe[1]);
                u.w[1] = cvtpk(pe[2], pe[3]);
                pf[qi] = u.v;
            }

            __builtin_amdgcn_s_setprio(1);
#pragma unroll
            for (int qi = 0; qi < 2; ++qi)
                lacc[qi] = __builtin_amdgcn_mfma_f32_16x16x16bf16_1k(
                    pf[qi], vone, lacc[qi], 0, 0, 0);
#pragma unroll
            for (int nd = 0; nd < 4; ++nd) {
                int d = nd * 16 + L;
                s16x4 vf = *(const s16x4*)&smem[LDSV + d * 128 +
                    (((ki * 16 + gq * 4) * 2) ^ ((d & 7) << 4))];
#pragma unroll
                for (int qi = 0; qi < 2; ++qi)
                    oacc[qi][nd] = __builtin_amdgcn_mfma_f32_16x16x16bf16_1k(
                        pf[qi], vf, oacc[qi][nd], 0, 0, 0);
            }
            __builtin_amdgcn_s_setprio(0);
        }
    }

    // staging + tables dead; per-wave [16][72] u16 transpose buffer.
    // lacc[qi][reg] already holds the full row-sum (lane-local).
    __syncthreads();
    u16* ot = (u16*)&smem[wv * 2304];
#pragma unroll
    for (int qi = 0; qi < 2; ++qi) {
#pragma unroll
        for (int reg = 0; reg < 4; ++reg) {
            float li = 1.f / lacc[qi][reg];
#pragma unroll
            for (int nd = 0; nd < 4; ++nd)
                ot[(gq * 4 + reg) * 72 + nd * 16 + L] = f2b(oacc[qi][nd][reg] * li);
        }
#pragma unroll
        for (int s = 0; s < 4; ++s) {
            int r = s * 4 + (lane >> 4);
            int c = (lane & 15) * 4;
            u16x4 a = *(const u16x4*)&ot[r * 72 + c];
            int q = q0 + qi * 16 + r;
            *(u16x4*)&oa16[(size_t)(p * KP + q) * CCH + h * DH + c] = a;
        }
    }
}

// ---------------------------------------------------------------------------
// Kernel C: proj GEMM: out = A16 @ (Bh+Bl)^T + bias  (frozen from R18)
// ---------------------------------------------------------------------------
__global__ __launch_bounds__(256, 3) void gemm_proj(
    const u16* __restrict__ A16,
    const u16* __restrict__ Bh, const u16* __restrict__ Bl,
    const float* __restrict__ bias, const int* __restrict__ order,
    float* __restrict__ out)
{
    __shared__ __align__(16) unsigned char smemP[49152];   // 48 KB
    u16* LA  = (u16*)smemP;
    u16* LBh = (u16*)&smemP[16384];
    u16* LBl = (u16*)&smemP[32768];

    const int t = threadIdx.x;
    const int lane = t & 63, wv = t >> 6;
    const int L = lane & 15, gq = lane >> 4;
    const int wr = wv >> 1, wc = wv & 1;

    const int orig = blockIdx.y * 3 + blockIdx.x;
    const int swz  = (orig & 7) * 192 + (orig >> 3);        // bijective (1536%8==0)
    const int n0 = (swz % 3) * 128;
    const int m0 = (swz / 3) * 128;

    f32x4 acc[4][4];
#pragma unroll
    for (int mi = 0; mi < 4; ++mi)
#pragma unroll
        for (int ni = 0; ni < 4; ++ni) acc[mi][ni] = (f32x4)0.f;

    for (int kc = 0; kc < K1; kc += 64) {
        __syncthreads();
#pragma unroll
        for (int i = 0; i < 4; ++i) {
            int ci = i * 256 + t;
            int r = ci >> 3, j = ci & 7;
            int c8 = (j ^ (r & 7)) * 8;
            gll16(A16 + (size_t)(m0 + r) * K1 + kc + c8, LA + ci * 8);
            size_t gb = (size_t)(n0 + r) * K1 + kc + c8;
            gll16(Bh + gb, LBh + ci * 8);
            gll16(Bl + gb, LBl + ci * 8);
        }
        __syncthreads();
#pragma unroll
        for (int ks = 0; ks < 2; ++ks) {
            s16x8 fah[4], fbh[4], fbl[4];
#pragma unroll
            for (int x = 0; x < 4; ++x) {
                int arow = wr * 64 + x * 16 + L;
                int brow = wc * 64 + x * 16 + L;
                int ka  = ((ks * 4 + gq) ^ (arow & 7)) * 8;
                int kb2 = ((ks * 4 + gq) ^ (brow & 7)) * 8;
                fah[x] = *(const s16x8*)&LA[arow * 64 + ka];
                fbh[x] = *(const s16x8*)&LBh[brow * 64 + kb2];
                fbl[x] = *(const s16x8*)&LBl[brow * 64 + kb2];
            }
#pragma unroll
            for (int mi = 0; mi < 4; ++mi)
#pragma unroll
                for (int ni = 0; ni < 4; ++ni) {
                    acc[mi][ni] = __builtin_amdgcn_mfma_f32_16x16x32_bf16(
                        fah[mi], fbh[ni], acc[mi][ni], 0, 0, 0);
                    acc[mi][ni] = __builtin_amdgcn_mfma_f32_16x16x32_bf16(
                        fah[mi], fbl[ni], acc[mi][ni], 0, 0, 0);
                }
        }
    }

    float bfrag[4];
#pragma unroll
    for (int ni = 0; ni < 4; ++ni) bfrag[ni] = bias[n0 + wc * 64 + ni * 16 + L];

    __syncthreads();
    float* otp = (float*)smemP + wv * 1088;   // [16][68] f32 per wave
#pragma unroll
    for (int mi = 0; mi < 4; ++mi) {
#pragma unroll
        for (int reg = 0; reg < 4; ++reg)
#pragma unroll
            for (int ni = 0; ni < 4; ++ni)
                otp[(gq * 4 + reg) * 68 + ni * 16 + L] = acc[mi][ni][reg] + bfrag[ni];
#pragma unroll
        for (int s = 0; s < 4; ++s) {
            int r = s * 4 + (lane >> 4);
            int c = (lane & 15) * 4;
            f32x4 a = *(const f32x4*)&otp[r * 68 + c];
            int j = m0 + wr * 64 + mi * 16 + r;
            float* dst = out + (size_t)order[j] * CCH + n0 + wc * 64 + c;
            *(f32x4*)dst = a;
        }
        __syncthreads();
    }
}

// ---------------------------------------------------------------------------
extern "C" void kernel_launch(void* const* d_in, const int* in_sizes, int n_in,
                              void* d_out, int out_size, void* d_ws, size_t ws_size,
                              hipStream_t stream) {
    const float* feat      = (const float*)d_in[0];
    const float* qkv_w     = (const float*)d_in[1];
    const float* qkv_b     = (const float*)d_in[2];
    const float* proj_w    = (const float*)d_in[3];
    const float* proj_b    = (const float*)d_in[4];
    const float* rpe_table = (const float*)d_in[5];
    const int*   order     = (const int*)d_in[6];
    const int*   gcoord    = (const int*)d_in[8];
    float* out = (float*)d_out;

    const size_t NC = (size_t)NPTS * CCH;
    u16* fh   = (u16*)d_ws;
    u16* qwh  = fh + NC;
    u16* pwh  = qwh + (size_t)1152 * 384;
    u16* pwl  = pwh + (size_t)384 * 384;
    u16* qs   = pwl + (size_t)384 * 384;
    u16* ks   = qs + NC;
    u16* vts  = ks + NC;
    u16* oa16 = vts + NC;
    unsigned* cpk_g = (unsigned*)(oa16 + NC);

    cast_bf16<<<(1152 * 384 / 4 + 255) / 256, 256, 0, stream>>>(qkv_w, qwh, 1152 * 384 / 4);
    split_arr<<<(384 * 384 / 4 + 255) / 256, 256, 0, stream>>>(proj_w, pwh, pwl, 384 * 384 / 4);
    gather_h<<<NPTS * 96 / 256, 256, 0, stream>>>(feat, order, fh);
    pack_coords<<<NPTS / 256, 256, 0, stream>>>(order, gcoord, cpk_g);

    gemm_qkv<<<dim3(9, NPTS / 128), 256, 0, stream>>>(
        fh, qwh, qkv_b, qs, ks, vts);
    attn_mfma<<<dim3(NPATCH, NH), 512, 0, stream>>>(
        qs, ks, vts, cpk_g, rpe_table, oa16);
    gemm_proj<<<dim3(3, NPTS / 128), 256, 0, stream>>>(
        oa16, pwh, pwl, proj_b, order, out);
}

// Round 22
// 234.068 us; speedup vs baseline: 1.0231x; 1.0149x over previous
//
#include <hip/hip_runtime.h>
#include <hip/hip_bf16.h>

// Problem constants
#define NPTS   65536
#define CCH    384
#define NH     6
#define DH     64
#define KP     256   // patch size
#define NPATCH 256   // NPTS / KP
#define PB     20    // POS_BND
#define RNUM   41    // 2*PB+1
#define K1     384   // GEMM inner dim
#define LOG2E  1.44269504088896f

typedef float f32x4 __attribute__((ext_vector_type(4)));
typedef short s16x8 __attribute__((ext_vector_type(8)));
typedef short s16x4 __attribute__((ext_vector_type(4)));
typedef unsigned u32x4 __attribute__((ext_vector_type(4)));
typedef unsigned short u16;
typedef u16 u16x4 __attribute__((ext_vector_type(4)));

static __device__ __forceinline__ u16 f2b(float f) {
    union { __hip_bfloat16 h; u16 u; } cv;
    cv.h = __float2bfloat16(f);
    return cv.u;
}
static __device__ __forceinline__ float b2f(u16 u) {
    union { float f; unsigned v; } cv; cv.v = ((unsigned)u) << 16; return cv.f;
}
static __device__ __forceinline__ void split1(float x, u16& h, u16& l) {
    h = f2b(x);
    l = f2b(x - b2f(h));
}
static __device__ __forceinline__ unsigned cvtpk(float a, float b) {
    unsigned r;
    asm("v_cvt_pk_bf16_f32 %0, %1, %2" : "=v"(r) : "v"(a), "v"(b));
    return r;
}
static __device__ __forceinline__ float exp2r(float x) {
    float r;
    asm("v_exp_f32 %0, %1" : "=v"(r) : "v"(x));
    return r;
}
// packed i16 pair ops (VOP3P)
static __device__ __forceinline__ unsigned pksub(unsigned a, unsigned b) {
    unsigned r;
    asm("v_pk_sub_i16 %0, %1, %2" : "=v"(r) : "v"(a), "v"(b));
    return r;
}
static __device__ __forceinline__ unsigned pkmax0(unsigned a) {
    unsigned r;
    asm("v_pk_max_i16 %0, %1, 0" : "=v"(r) : "v"(a));
    return r;
}
static __device__ __forceinline__ unsigned pkmin40(unsigned a, unsigned c40) {
    unsigned r;
    asm("v_pk_min_i16 %0, %1, %2" : "=v"(r) : "v"(a), "v"(c40));
    return r;
}

typedef __attribute__((address_space(3))) unsigned lds_u;
typedef const __attribute__((address_space(1))) unsigned glob_u;
static __device__ __forceinline__ void gll16(const void* g, void* l) {
    __builtin_amdgcn_global_load_lds((glob_u*)g, (lds_u*)l, 16, 0, 0);
}

// ---------------------------------------------------------------------------
// Prep kernels
// ---------------------------------------------------------------------------
__global__ __launch_bounds__(256) void split_arr(
    const float* __restrict__ s, u16* __restrict__ h, u16* __restrict__ l, int n4)
{
    int i = blockIdx.x * 256 + threadIdx.x;
    if (i >= n4) return;
    float4 v = ((const float4*)s)[i];
    u16 h0, l0, h1, l1, h2, l2, h3, l3;
    split1(v.x, h0, l0); split1(v.y, h1, l1);
    split1(v.z, h2, l2); split1(v.w, h3, l3);
    u16x4 hv, lv;
    hv[0] = h0; hv[1] = h1; hv[2] = h2; hv[3] = h3;
    lv[0] = l0; lv[1] = l1; lv[2] = l2; lv[3] = l3;
    *(u16x4*)&h[(size_t)i * 4] = hv;
    *(u16x4*)&l[(size_t)i * 4] = lv;
}

__global__ __launch_bounds__(256) void cast_bf16(
    const float* __restrict__ s, u16* __restrict__ d, int n4)
{
    int i = blockIdx.x * 256 + threadIdx.x;
    if (i >= n4) return;
    float4 v = ((const float4*)s)[i];
    u16x4 hv;
    hv[0] = f2b(v.x); hv[1] = f2b(v.y); hv[2] = f2b(v.z); hv[3] = f2b(v.w);
    *(u16x4*)&d[(size_t)i * 4] = hv;
}

// Gather fh = bf16(feat[order[j]])
__global__ __launch_bounds__(256) void gather_h(
    const float* __restrict__ feat, const int* __restrict__ order,
    u16* __restrict__ fh)
{
    int i = blockIdx.x * 256 + threadIdx.x;   // over NPTS*96 float4s
    int r = i / 96, c4 = i % 96;
    int o = order[r];
    float4 v = *((const float4*)(feat + (size_t)o * CCH) + c4);
    u16x4 hv;
    hv[0] = f2b(v.x); hv[1] = f2b(v.y); hv[2] = f2b(v.z); hv[3] = f2b(v.w);
    *(u16x4*)&fh[(size_t)r * CCH + c4 * 4] = hv;
}

// coords: cxy = x | y<<16 ; cz = z (u16)
__global__ __launch_bounds__(256) void pack_coords(
    const int* __restrict__ order, const int* __restrict__ gcoord,
    unsigned* __restrict__ cxy_g, u16* __restrict__ cz_g)
{
    int j = blockIdx.x * 256 + threadIdx.x;
    int o = order[j];
    const int* gc = gcoord + (size_t)o * 3;
    cxy_g[j] = (unsigned)gc[0] | ((unsigned)gc[1] << 16);
    cz_g[j]  = (u16)gc[2];
}

// ---------------------------------------------------------------------------
// Kernel A: 1-term bf16 GEMM (qkv): C = Ah*Bh  (frozen from R20)
// ---------------------------------------------------------------------------
__global__ __launch_bounds__(256, 4) void gemm_qkv(
    const u16* __restrict__ Ah, const u16* __restrict__ Bh,
    const float* __restrict__ bias,
    u16* __restrict__ q_out, u16* __restrict__ k_out, u16* __restrict__ vt_out)
{
    __shared__ __align__(16) u16 lds[2 * 128 * 64];   // 32 KB
    u16* LAh = lds;
    u16* LBh = lds + 128 * 64;

    const int t = threadIdx.x;
    const int lane = t & 63, wv = t >> 6;
    const int L = lane & 15, gq = lane >> 4;
    const int wr = wv >> 1, wc = wv & 1;

    const int orig = blockIdx.y * 9 + blockIdx.x;
    const int swz  = (orig & 7) * 576 + (orig >> 3);        // bijective (4608%8==0)
    const int n0 = (swz % 9) * 128;
    const int m0 = (swz / 9) * 128;

    f32x4 acc[4][4];
#pragma unroll
    for (int mi = 0; mi < 4; ++mi)
#pragma unroll
        for (int ni = 0; ni < 4; ++ni) acc[mi][ni] = (f32x4)0.f;

    for (int kc = 0; kc < K1; kc += 64) {
        __syncthreads();
#pragma unroll
        for (int i = 0; i < 4; ++i) {
            int ci = i * 256 + t;
            int r = ci >> 3, j = ci & 7;
            int c8 = (j ^ (r & 7)) * 8;
            gll16(Ah + (size_t)(m0 + r) * K1 + kc + c8, LAh + ci * 8);
            gll16(Bh + (size_t)(n0 + r) * K1 + kc + c8, LBh + ci * 8);
        }
        __syncthreads();
#pragma unroll
        for (int ks = 0; ks < 2; ++ks) {
            s16x8 fah[4], fbh[4];
#pragma unroll
            for (int x = 0; x < 4; ++x) {
                int arow = wr * 64 + x * 16 + L;
                int brow = wc * 64 + x * 16 + L;
                int ka  = ((ks * 4 + gq) ^ (arow & 7)) * 8;
                int kb2 = ((ks * 4 + gq) ^ (brow & 7)) * 8;
                fah[x] = *(const s16x8*)&LAh[arow * 64 + ka];
                fbh[x] = *(const s16x8*)&LBh[brow * 64 + kb2];
            }
#pragma unroll
            for (int mi = 0; mi < 4; ++mi)
#pragma unroll
                for (int ni = 0; ni < 4; ++ni)
                    acc[mi][ni] = __builtin_amdgcn_mfma_f32_16x16x32_bf16(
                        fah[mi], fbh[ni], acc[mi][ni], 0, 0, 0);
        }
    }

    float bfrag[4];
#pragma unroll
    for (int ni = 0; ni < 4; ++ni) bfrag[ni] = bias[n0 + wc * 64 + ni * 16 + L];

    const int cq   = n0 + wc * 64;
    const int ssel = cq / CCH;
    const int hh   = (cq % CCH) / DH;

    if (ssel == 2) {
#pragma unroll
        for (int mi = 0; mi < 4; ++mi) {
            int jb = m0 + wr * 64 + mi * 16;
            int p = jb >> 8, kr0 = (jb & 255) + gq * 4;
            size_t hb = (size_t)(p * NH + hh) * DH;
#pragma unroll
            for (int ni = 0; ni < 4; ++ni) {
                int d = ni * 16 + L;
                u16x4 w;
#pragma unroll
                for (int reg = 0; reg < 4; ++reg)
                    w[reg] = f2b(acc[mi][ni][reg] + bfrag[ni]);
                int kswz = (kr0 & ~63) + ((kr0 & 63) ^ ((d & 7) << 3));
                *(u16x4*)&vt_out[(hb + d) * KP + kswz] = w;
            }
        }
    } else if (ssel == 1) {
#pragma unroll
        for (int mi = 0; mi < 4; ++mi)
#pragma unroll
            for (int reg = 0; reg < 4; ++reg) {
                int j = m0 + wr * 64 + mi * 16 + gq * 4 + reg;
                int kk = j & 255;
                u16* orow = k_out + ((size_t)((j >> 8) * NH + hh) * KP + kk) * DH;
                int sw = (kk & 7) << 3;
#pragma unroll
                for (int ni = 0; ni < 4; ++ni)
                    orow[(ni * 16 + L) ^ sw] = f2b(acc[mi][ni][reg] + bfrag[ni]);
            }
    } else {
        const float qscl = 0.125f * LOG2E;
#pragma unroll
        for (int mi = 0; mi < 4; ++mi)
#pragma unroll
            for (int reg = 0; reg < 4; ++reg) {
                int j = m0 + wr * 64 + mi * 16 + gq * 4 + reg;
                u16* orow = q_out + ((size_t)((j >> 8) * NH + hh) * KP + (j & 255)) * DH;
#pragma unroll
                for (int ni = 0; ni < 4; ++ni)
                    orow[ni * 16 + L] = f2b((acc[mi][ni][reg] + bfrag[ni]) * qscl);
            }
    }
}

// ---------------------------------------------------------------------------
// Kernel B: swapped-operand MFMA flash attention per (patch, head).
// exp2-domain softmax; MFMA ones-column row-sum; packed-i16 coord clamps.
// ---------------------------------------------------------------------------
#define LDSK  0
#define LDSV  8192
#define CXYO  16384                 // 256 u32 = 1024 B
#define CZO   17408                 // 256 u16 = 512 B
#define RPEXY 17920                 // 1681 f32 = 6724 B
#define RPEZ  24644                 // 41 f32 = 164 B
#define SMEMSZ 24832

__global__ __launch_bounds__(512, 4) void attn_mfma(
    const u16* __restrict__ q_s, const u16* __restrict__ k_s,
    const u16* __restrict__ vt_s, const unsigned* __restrict__ cxy_g,
    const u16* __restrict__ cz_g,
    const float* __restrict__ rpe_table, u16* __restrict__ oa16)
{
    __shared__ __align__(16) unsigned char smem[SMEMSZ];
    unsigned* cxy   = (unsigned*)&smem[CXYO];
    u16*      czs   = (u16*)&smem[CZO];
    float*    rpexy = (float*)&smem[RPEXY];
    float*    rpez  = (float*)&smem[RPEZ];

    const int t    = threadIdx.x;
    const int p    = blockIdx.x, h = blockIdx.y;
    const int lane = t & 63, wv = t >> 6;
    const int L    = lane & 15, gq = lane >> 4;
    const int q0   = wv * 32;
    const size_t base = (size_t)(p * NH + h) * KP * DH;

    if (t < KP) {
        cxy[t] = cxy_g[p * KP + t];
        czs[t] = cz_g[p * KP + t];
    }
    for (int idx = t; idx < RNUM * RNUM; idx += 512) {
        int ix = idx % RNUM, iy = idx / RNUM;
        rpexy[idx] = (rpe_table[ix * NH + h] + rpe_table[(RNUM + iy) * NH + h]) * LOG2E;
    }
    if (t < RNUM) rpez[t] = rpe_table[(2 * RNUM + t) * NH + h] * LOG2E;
    __syncthreads();

    // q coords with +PB folded into both halves (carry-free: x+20 < 2^16)
    unsigned qxyb[2];
    int qzb[2];
    const unsigned c40 = 0x00280028u;
#pragma unroll
    for (int qi = 0; qi < 2; ++qi) {
        qxyb[qi] = cxy[q0 + qi * 16 + L] + 0x00140014u;
        qzb[qi]  = (int)czs[q0 + qi * 16 + L] + PB;
    }

    s16x8 aq[2][2];
#pragma unroll
    for (int qi = 0; qi < 2; ++qi)
#pragma unroll
        for (int ks = 0; ks < 2; ++ks)
            aq[qi][ks] = *(const s16x8*)&q_s[base +
                (size_t)(q0 + qi * 16 + L) * DH + ks * 32 + gq * 8];

    f32x4 oacc[2][4];
    f32x4 lacc[2];
#pragma unroll
    for (int qi = 0; qi < 2; ++qi) {
#pragma unroll
        for (int nd = 0; nd < 4; ++nd) oacc[qi][nd] = (f32x4)0.f;
        lacc[qi] = (f32x4)0.f;
    }
    s16x4 vone;
    vone[0] = (short)0x3F80; vone[1] = (short)0x3F80;
    vone[2] = (short)0x3F80; vone[3] = (short)0x3F80;

    const int srow = t >> 3;
    const int sc8  = (t & 7) * 8;

    for (int kb = 0; kb < 4; ++kb) {
        __syncthreads();
        {
            const u16* kg = k_s + base + (size_t)(kb * 64 + srow) * DH + sc8;
            gll16(kg, &smem[LDSK + t * 16]);
            const u16* vg = vt_s + base + (size_t)srow * KP + kb * 64 + sc8;
            gll16(vg, &smem[LDSV + t * 16]);
        }
        __syncthreads();

#pragma unroll
        for (int ki = 0; ki < 4; ++ki) {
            const int krow = ki * 16 + L;
            const int kxor = (krow & 7) << 4;
            s16x8 ak0 = *(const s16x8*)&smem[LDSK + krow * 128 + ((gq * 16) ^ kxor)];
            s16x8 ak1 = *(const s16x8*)&smem[LDSK + krow * 128 + ((64 + gq * 16) ^ kxor)];

            f32x4 sacc[2];
            __builtin_amdgcn_s_setprio(1);
#pragma unroll
            for (int qi = 0; qi < 2; ++qi) {
                sacc[qi] = __builtin_amdgcn_mfma_f32_16x16x32_bf16(
                    ak0, aq[qi][0], (f32x4)0.f, 0, 0, 0);
                sacc[qi] = __builtin_amdgcn_mfma_f32_16x16x32_bf16(
                    ak1, aq[qi][1], sacc[qi], 0, 0, 0);
            }
            __builtin_amdgcn_s_setprio(0);

            u32x4 kxy4 = *(const u32x4*)&cxy[kb * 64 + ki * 16 + gq * 4];
            u16x4 kz4  = *(const u16x4*)&czs[kb * 64 + ki * 16 + gq * 4];

            s16x4 pf[2];
#pragma unroll
            for (int qi = 0; qi < 2; ++qi) {
                float pe[4];
#pragma unroll
                for (int j = 0; j < 4; ++j) {
                    unsigned rel = pkmin40(pkmax0(pksub(qxyb[qi], kxy4[j])), c40);
                    int ix = (int)(rel & 0xFFFFu);
                    int iy = (int)(rel >> 16);
                    int iz = qzb[qi] - (int)kz4[j]; iz = iz < 0 ? 0 : (iz > 40 ? 40 : iz);
                    float sv = sacc[qi][j] + rpexy[iy * RNUM + ix] + rpez[iz];
                    pe[j] = exp2r(sv);
                }
                union { unsigned w[2]; s16x4 v; } u;
                u.w[0] = cvtpk(pe[0], pe[1]);
                u.w[1] = cvtpk(pe[2], pe[3]);
                pf[qi] = u.v;
            }

            __builtin_amdgcn_s_setprio(1);
#pragma unroll
            for (int qi = 0; qi < 2; ++qi)
                lacc[qi] = __builtin_amdgcn_mfma_f32_16x16x16bf16_1k(
                    pf[qi], vone, lacc[qi], 0, 0, 0);
#pragma unroll
            for (int nd = 0; nd < 4; ++nd) {
                int d = nd * 16 + L;
                s16x4 vf = *(const s16x4*)&smem[LDSV + d * 128 +
                    (((ki * 16 + gq * 4) * 2) ^ ((d & 7) << 4))];
#pragma unroll
                for (int qi = 0; qi < 2; ++qi)
                    oacc[qi][nd] = __builtin_amdgcn_mfma_f32_16x16x16bf16_1k(
                        pf[qi], vf, oacc[qi][nd], 0, 0, 0);
            }
            __builtin_amdgcn_s_setprio(0);
        }
    }

    // staging + tables dead; per-wave [16][72] u16 transpose buffer.
    __syncthreads();
    u16* ot = (u16*)&smem[wv * 2304];
#pragma unroll
    for (int qi = 0; qi < 2; ++qi) {
#pragma unroll
        for (int reg = 0; reg < 4; ++reg) {
            float li = 1.f / lacc[qi][reg];
#pragma unroll
            for (int nd = 0; nd < 4; ++nd)
                ot[(gq * 4 + reg) * 72 + nd * 16 + L] = f2b(oacc[qi][nd][reg] * li);
        }
#pragma unroll
        for (int s = 0; s < 4; ++s) {
            int r = s * 4 + (lane >> 4);
            int c = (lane & 15) * 4;
            u16x4 a = *(const u16x4*)&ot[r * 72 + c];
            int q = q0 + qi * 16 + r;
            *(u16x4*)&oa16[(size_t)(p * KP + q) * CCH + h * DH + c] = a;
        }
    }
}

// ---------------------------------------------------------------------------
// Kernel C: proj GEMM: out = A16 @ (Bh+Bl)^T + bias  (frozen from R18)
// ---------------------------------------------------------------------------
__global__ __launch_bounds__(256, 3) void gemm_proj(
    const u16* __restrict__ A16,
    const u16* __restrict__ Bh, const u16* __restrict__ Bl,
    const float* __restrict__ bias, const int* __restrict__ order,
    float* __restrict__ out)
{
    __shared__ __align__(16) unsigned char smemP[49152];   // 48 KB
    u16* LA  = (u16*)smemP;
    u16* LBh = (u16*)&smemP[16384];
    u16* LBl = (u16*)&smemP[32768];

    const int t = threadIdx.x;
    const int lane = t & 63, wv = t >> 6;
    const int L = lane & 15, gq = lane >> 4;
    const int wr = wv >> 1, wc = wv & 1;

    const int orig = blockIdx.y * 3 + blockIdx.x;
    const int swz  = (orig & 7) * 192 + (orig >> 3);        // bijective (1536%8==0)
    const int n0 = (swz % 3) * 128;
    const int m0 = (swz / 3) * 128;

    f32x4 acc[4][4];
#pragma unroll
    for (int mi = 0; mi < 4; ++mi)
#pragma unroll
        for (int ni = 0; ni < 4; ++ni) acc[mi][ni] = (f32x4)0.f;

    for (int kc = 0; kc < K1; kc += 64) {
        __syncthreads();
#pragma unroll
        for (int i = 0; i < 4; ++i) {
            int ci = i * 256 + t;
            int r = ci >> 3, j = ci & 7;
            int c8 = (j ^ (r & 7)) * 8;
            gll16(A16 + (size_t)(m0 + r) * K1 + kc + c8, LA + ci * 8);
            size_t gb = (size_t)(n0 + r) * K1 + kc + c8;
            gll16(Bh + gb, LBh + ci * 8);
            gll16(Bl + gb, LBl + ci * 8);
        }
        __syncthreads();
#pragma unroll
        for (int ks = 0; ks < 2; ++ks) {
            s16x8 fah[4], fbh[4], fbl[4];
#pragma unroll
            for (int x = 0; x < 4; ++x) {
                int arow = wr * 64 + x * 16 + L;
                int brow = wc * 64 + x * 16 + L;
                int ka  = ((ks * 4 + gq) ^ (arow & 7)) * 8;
                int kb2 = ((ks * 4 + gq) ^ (brow & 7)) * 8;
                fah[x] = *(const s16x8*)&LA[arow * 64 + ka];
                fbh[x] = *(const s16x8*)&LBh[brow * 64 + kb2];
                fbl[x] = *(const s16x8*)&LBl[brow * 64 + kb2];
            }
#pragma unroll
            for (int mi = 0; mi < 4; ++mi)
#pragma unroll
                for (int ni = 0; ni < 4; ++ni) {
                    acc[mi][ni] = __builtin_amdgcn_mfma_f32_16x16x32_bf16(
                        fah[mi], fbh[ni], acc[mi][ni], 0, 0, 0);
                    acc[mi][ni] = __builtin_amdgcn_mfma_f32_16x16x32_bf16(
                        fah[mi], fbl[ni], acc[mi][ni], 0, 0, 0);
                }
        }
    }

    float bfrag[4];
#pragma unroll
    for (int ni = 0; ni < 4; ++ni) bfrag[ni] = bias[n0 + wc * 64 + ni * 16 + L];

    __syncthreads();
    float* otp = (float*)smemP + wv * 1088;   // [16][68] f32 per wave
#pragma unroll
    for (int mi = 0; mi < 4; ++mi) {
#pragma unroll
        for (int reg = 0; reg < 4; ++reg)
#pragma unroll
            for (int ni = 0; ni < 4; ++ni)
                otp[(gq * 4 + reg) * 68 + ni * 16 + L] = acc[mi][ni][reg] + bfrag[ni];
#pragma unroll
        for (int s = 0; s < 4; ++s) {
            int r = s * 4 + (lane >> 4);
            int c = (lane & 15) * 4;
            f32x4 a = *(const f32x4*)&otp[r * 68 + c];
            int j = m0 + wr * 64 + mi * 16 + r;
            float* dst = out + (size_t)order[j] * CCH + n0 + wc * 64 + c;
            *(f32x4*)dst = a;
        }
        __syncthreads();
    }
}

// ---------------------------------------------------------------------------
extern "C" void kernel_launch(void* const* d_in, const int* in_sizes, int n_in,
                              void* d_out, int out_size, void* d_ws, size_t ws_size,
                              hipStream_t stream) {
    const float* feat      = (const float*)d_in[0];
    const float* qkv_w     = (const float*)d_in[1];
    const float* qkv_b     = (const float*)d_in[2];
    const float* proj_w    = (const float*)d_in[3];
    const float* proj_b    = (const float*)d_in[4];
    const float* rpe_table = (const float*)d_in[5];
    const int*   order     = (const int*)d_in[6];
    const int*   gcoord    = (const int*)d_in[8];
    float* out = (float*)d_out;

    const size_t NC = (size_t)NPTS * CCH;
    u16* fh   = (u16*)d_ws;
    u16* qwh  = fh + NC;
    u16* pwh  = qwh + (size_t)1152 * 384;
    u16* pwl  = pwh + (size_t)384 * 384;
    u16* qs   = pwl + (size_t)384 * 384;
    u16* ks   = qs + NC;
    u16* vts  = ks + NC;
    u16* oa16 = vts + NC;
    unsigned* cxy_g = (unsigned*)(oa16 + NC);
    u16* cz_g = (u16*)(cxy_g + NPTS);

    cast_bf16<<<(1152 * 384 / 4 + 255) / 256, 256, 0, stream>>>(qkv_w, qwh, 1152 * 384 / 4);
    split_arr<<<(384 * 384 / 4 + 255) / 256, 256, 0, stream>>>(proj_w, pwh, pwl, 384 * 384 / 4);
    gather_h<<<NPTS * 96 / 256, 256, 0, stream>>>(feat, order, fh);
    pack_coords<<<NPTS / 256, 256, 0, stream>>>(order, gcoord, cxy_g, cz_g);

    gemm_qkv<<<dim3(9, NPTS / 128), 256, 0, stream>>>(
        fh, qwh, qkv_b, qs, ks, vts);
    attn_mfma<<<dim3(NPATCH, NH), 512, 0, stream>>>(
        qs, ks, vts, cxy_g, cz_g, rpe_table, oa16);
    gemm_proj<<<dim3(3, NPTS / 128), 256, 0, stream>>>(
        oa16, pwh, pwl, proj_b, order, out);
}

// Round 23
// 231.726 us; speedup vs baseline: 1.0334x; 1.0101x over previous
//
#include <hip/hip_runtime.h>
#include <hip/hip_bf16.h>

// Problem constants
#define NPTS   65536
#define CCH    384
#define NH     6
#define DH     64
#define KP     256   // patch size
#define NPATCH 256   // NPTS / KP
#define PB     20    // POS_BND
#define RNUM   41    // 2*PB+1
#define K1     384   // GEMM inner dim
#define LOG2E  1.44269504088896f

typedef float f32x4 __attribute__((ext_vector_type(4)));
typedef short s16x8 __attribute__((ext_vector_type(8)));
typedef short s16x4 __attribute__((ext_vector_type(4)));
typedef unsigned u32x4 __attribute__((ext_vector_type(4)));
typedef unsigned short u16;
typedef u16 u16x4 __attribute__((ext_vector_type(4)));

static __device__ __forceinline__ u16 f2b(float f) {
    union { __hip_bfloat16 h; u16 u; } cv;
    cv.h = __float2bfloat16(f);
    return cv.u;
}
static __device__ __forceinline__ float b2f(u16 u) {
    union { float f; unsigned v; } cv; cv.v = ((unsigned)u) << 16; return cv.f;
}
static __device__ __forceinline__ void split1(float x, u16& h, u16& l) {
    h = f2b(x);
    l = f2b(x - b2f(h));
}
static __device__ __forceinline__ unsigned cvtpk(float a, float b) {
    unsigned r;
    asm("v_cvt_pk_bf16_f32 %0, %1, %2" : "=v"(r) : "v"(a), "v"(b));
    return r;
}
static __device__ __forceinline__ float exp2r(float x) {
    float r;
    asm("v_exp_f32 %0, %1" : "=v"(r) : "v"(x));
    return r;
}
// packed i16 pair ops (VOP3P)
static __device__ __forceinline__ unsigned pksub(unsigned a, unsigned b) {
    unsigned r;
    asm("v_pk_sub_i16 %0, %1, %2" : "=v"(r) : "v"(a), "v"(b));
    return r;
}
static __device__ __forceinline__ unsigned pkmax0(unsigned a) {
    unsigned r;
    asm("v_pk_max_i16 %0, %1, 0" : "=v"(r) : "v"(a));
    return r;
}
static __device__ __forceinline__ unsigned pkmin40(unsigned a, unsigned c40) {
    unsigned r;
    asm("v_pk_min_i16 %0, %1, %2" : "=v"(r) : "v"(a), "v"(c40));
    return r;
}

typedef __attribute__((address_space(3))) unsigned lds_u;
typedef const __attribute__((address_space(1))) unsigned glob_u;
static __device__ __forceinline__ void gll16(const void* g, void* l) {
    __builtin_amdgcn_global_load_lds((glob_u*)g, (lds_u*)l, 16, 0, 0);
}

// ---------------------------------------------------------------------------
// Prep kernels
// ---------------------------------------------------------------------------
__global__ __launch_bounds__(256) void split_arr(
    const float* __restrict__ s, u16* __restrict__ h, u16* __restrict__ l, int n4)
{
    int i = blockIdx.x * 256 + threadIdx.x;
    if (i >= n4) return;
    float4 v = ((const float4*)s)[i];
    u16 h0, l0, h1, l1, h2, l2, h3, l3;
    split1(v.x, h0, l0); split1(v.y, h1, l1);
    split1(v.z, h2, l2); split1(v.w, h3, l3);
    u16x4 hv, lv;
    hv[0] = h0; hv[1] = h1; hv[2] = h2; hv[3] = h3;
    lv[0] = l0; lv[1] = l1; lv[2] = l2; lv[3] = l3;
    *(u16x4*)&h[(size_t)i * 4] = hv;
    *(u16x4*)&l[(size_t)i * 4] = lv;
}

__global__ __launch_bounds__(256) void cast_bf16(
    const float* __restrict__ s, u16* __restrict__ d, int n4)
{
    int i = blockIdx.x * 256 + threadIdx.x;
    if (i >= n4) return;
    float4 v = ((const float4*)s)[i];
    u16x4 hv;
    hv[0] = f2b(v.x); hv[1] = f2b(v.y); hv[2] = f2b(v.z); hv[3] = f2b(v.w);
    *(u16x4*)&d[(size_t)i * 4] = hv;
}

// Gather fh = bf16(feat[order[j]])
__global__ __launch_bounds__(256) void gather_h(
    const float* __restrict__ feat, const int* __restrict__ order,
    u16* __restrict__ fh)
{
    int i = blockIdx.x * 256 + threadIdx.x;   // over NPTS*96 float4s
    int r = i / 96, c4 = i % 96;
    int o = order[r];
    float4 v = *((const float4*)(feat + (size_t)o * CCH) + c4);
    u16x4 hv;
    hv[0] = f2b(v.x); hv[1] = f2b(v.y); hv[2] = f2b(v.z); hv[3] = f2b(v.w);
    *(u16x4*)&fh[(size_t)r * CCH + c4 * 4] = hv;
}

// coords: cxy = x | y<<16 ; cz = z (u16)
__global__ __launch_bounds__(256) void pack_coords(
    const int* __restrict__ order, const int* __restrict__ gcoord,
    unsigned* __restrict__ cxy_g, u16* __restrict__ cz_g)
{
    int j = blockIdx.x * 256 + threadIdx.x;
    int o = order[j];
    const int* gc = gcoord + (size_t)o * 3;
    cxy_g[j] = (unsigned)gc[0] | ((unsigned)gc[1] << 16);
    cz_g[j]  = (u16)gc[2];
}

// ---------------------------------------------------------------------------
// Kernel A: 1-term bf16 GEMM (qkv): C = Ah*Bh  (frozen)
// ---------------------------------------------------------------------------
__global__ __launch_bounds__(256, 4) void gemm_qkv(
    const u16* __restrict__ Ah, const u16* __restrict__ Bh,
    const float* __restrict__ bias,
    u16* __restrict__ q_out, u16* __restrict__ k_out, u16* __restrict__ vt_out)
{
    __shared__ __align__(16) u16 lds[2 * 128 * 64];   // 32 KB
    u16* LAh = lds;
    u16* LBh = lds + 128 * 64;

    const int t = threadIdx.x;
    const int lane = t & 63, wv = t >> 6;
    const int L = lane & 15, gq = lane >> 4;
    const int wr = wv >> 1, wc = wv & 1;

    const int orig = blockIdx.y * 9 + blockIdx.x;
    const int swz  = (orig & 7) * 576 + (orig >> 3);        // bijective (4608%8==0)
    const int n0 = (swz % 9) * 128;
    const int m0 = (swz / 9) * 128;

    f32x4 acc[4][4];
#pragma unroll
    for (int mi = 0; mi < 4; ++mi)
#pragma unroll
        for (int ni = 0; ni < 4; ++ni) acc[mi][ni] = (f32x4)0.f;

    for (int kc = 0; kc < K1; kc += 64) {
        __syncthreads();
#pragma unroll
        for (int i = 0; i < 4; ++i) {
            int ci = i * 256 + t;
            int r = ci >> 3, j = ci & 7;
            int c8 = (j ^ (r & 7)) * 8;
            gll16(Ah + (size_t)(m0 + r) * K1 + kc + c8, LAh + ci * 8);
            gll16(Bh + (size_t)(n0 + r) * K1 + kc + c8, LBh + ci * 8);
        }
        __syncthreads();
#pragma unroll
        for (int ks = 0; ks < 2; ++ks) {
            s16x8 fah[4], fbh[4];
#pragma unroll
            for (int x = 0; x < 4; ++x) {
                int arow = wr * 64 + x * 16 + L;
                int brow = wc * 64 + x * 16 + L;
                int ka  = ((ks * 4 + gq) ^ (arow & 7)) * 8;
                int kb2 = ((ks * 4 + gq) ^ (brow & 7)) * 8;
                fah[x] = *(const s16x8*)&LAh[arow * 64 + ka];
                fbh[x] = *(const s16x8*)&LBh[brow * 64 + kb2];
            }
#pragma unroll
            for (int mi = 0; mi < 4; ++mi)
#pragma unroll
                for (int ni = 0; ni < 4; ++ni)
                    acc[mi][ni] = __builtin_amdgcn_mfma_f32_16x16x32_bf16(
                        fah[mi], fbh[ni], acc[mi][ni], 0, 0, 0);
        }
    }

    float bfrag[4];
#pragma unroll
    for (int ni = 0; ni < 4; ++ni) bfrag[ni] = bias[n0 + wc * 64 + ni * 16 + L];

    const int cq   = n0 + wc * 64;
    const int ssel = cq / CCH;
    const int hh   = (cq % CCH) / DH;

    if (ssel == 2) {
#pragma unroll
        for (int mi = 0; mi < 4; ++mi) {
            int jb = m0 + wr * 64 + mi * 16;
            int p = jb >> 8, kr0 = (jb & 255) + gq * 4;
            size_t hb = (size_t)(p * NH + hh) * DH;
#pragma unroll
            for (int ni = 0; ni < 4; ++ni) {
                int d = ni * 16 + L;
                u16x4 w;
#pragma unroll
                for (int reg = 0; reg < 4; ++reg)
                    w[reg] = f2b(acc[mi][ni][reg] + bfrag[ni]);
                int kswz = (kr0 & ~63) + ((kr0 & 63) ^ ((d & 7) << 3));
                *(u16x4*)&vt_out[(hb + d) * KP + kswz] = w;
            }
        }
    } else if (ssel == 1) {
#pragma unroll
        for (int mi = 0; mi < 4; ++mi)
#pragma unroll
            for (int reg = 0; reg < 4; ++reg) {
                int j = m0 + wr * 64 + mi * 16 + gq * 4 + reg;
                int kk = j & 255;
                u16* orow = k_out + ((size_t)((j >> 8) * NH + hh) * KP + kk) * DH;
                int sw = (kk & 7) << 3;
#pragma unroll
                for (int ni = 0; ni < 4; ++ni)
                    orow[(ni * 16 + L) ^ sw] = f2b(acc[mi][ni][reg] + bfrag[ni]);
            }
    } else {
        const float qscl = 0.125f * LOG2E;
#pragma unroll
        for (int mi = 0; mi < 4; ++mi)
#pragma unroll
            for (int reg = 0; reg < 4; ++reg) {
                int j = m0 + wr * 64 + mi * 16 + gq * 4 + reg;
                u16* orow = q_out + ((size_t)((j >> 8) * NH + hh) * KP + (j & 255)) * DH;
#pragma unroll
                for (int ni = 0; ni < 4; ++ni)
                    orow[ni * 16 + L] = f2b((acc[mi][ni][reg] + bfrag[ni]) * qscl);
            }
    }
}

// ---------------------------------------------------------------------------
// Kernel B: swapped-operand MFMA flash attention per (patch, head).
// WHOLE K and V^T staged ONCE (74 KB LDS, 2 blocks/CU): zero barriers in
// the 16-slice k-loop. exp2 softmax; MFMA ones-column row-sum; pk-i16 clamps.
// ---------------------------------------------------------------------------
#define LDSK  0                      // 256 rows x 128 B = 32768
#define LDSV  32768                  // 64 d-rows x 512 B = 32768
#define CXYO  65536                  // 256 u32 = 1024
#define CZO   66560                  // 256 u16 = 512
#define RPEXY 67072                  // 1681 f32 = 6724 (pad 6784)
#define RPEZ  73856                  // 41 f32
#define SMEMSZ 74048

__global__ __launch_bounds__(512, 2) void attn_mfma(
    const u16* __restrict__ q_s, const u16* __restrict__ k_s,
    const u16* __restrict__ vt_s, const unsigned* __restrict__ cxy_g,
    const u16* __restrict__ cz_g,
    const float* __restrict__ rpe_table, u16* __restrict__ oa16)
{
    __shared__ __align__(16) unsigned char smem[SMEMSZ];
    unsigned* cxy   = (unsigned*)&smem[CXYO];
    u16*      czs   = (u16*)&smem[CZO];
    float*    rpexy = (float*)&smem[RPEXY];
    float*    rpez  = (float*)&smem[RPEZ];

    const int t    = threadIdx.x;
    const int p    = blockIdx.x, h = blockIdx.y;
    const int lane = t & 63, wv = t >> 6;
    const int L    = lane & 15, gq = lane >> 4;
    const int q0   = wv * 32;
    const size_t base = (size_t)(p * NH + h) * KP * DH;

    // ---- stage EVERYTHING once: K (2048 chunks), V^T (2048 chunks)
#pragma unroll
    for (int i = 0; i < 4; ++i) {
        int ci = i * 512 + t;
        int r = ci >> 3, j = ci & 7;            // K row, chunk
        gll16(k_s + base + (size_t)r * DH + j * 8, &smem[LDSK + ci * 16]);
        int d = ci >> 5, jc = ci & 31;          // V d-row, chunk
        gll16(vt_s + base + (size_t)d * KP + jc * 8, &smem[LDSV + ci * 16]);
    }
    if (t < KP) {
        cxy[t] = cxy_g[p * KP + t];
        czs[t] = cz_g[p * KP + t];
    }
    for (int idx = t; idx < RNUM * RNUM; idx += 512) {
        int ix = idx % RNUM, iy = idx / RNUM;
        rpexy[idx] = (rpe_table[ix * NH + h] + rpe_table[(RNUM + iy) * NH + h]) * LOG2E;
    }
    if (t < RNUM) rpez[t] = rpe_table[(2 * RNUM + t) * NH + h] * LOG2E;
    __syncthreads();

    unsigned qxyb[2];
    int qzb[2];
    const unsigned c40 = 0x00280028u;
#pragma unroll
    for (int qi = 0; qi < 2; ++qi) {
        qxyb[qi] = cxy[q0 + qi * 16 + L] + 0x00140014u;
        qzb[qi]  = (int)czs[q0 + qi * 16 + L] + PB;
    }

    s16x8 aq[2][2];
#pragma unroll
    for (int qi = 0; qi < 2; ++qi)
#pragma unroll
        for (int ks = 0; ks < 2; ++ks)
            aq[qi][ks] = *(const s16x8*)&q_s[base +
                (size_t)(q0 + qi * 16 + L) * DH + ks * 32 + gq * 8];

    f32x4 oacc[2][4];
    f32x4 lacc[2];
#pragma unroll
    for (int qi = 0; qi < 2; ++qi) {
#pragma unroll
        for (int nd = 0; nd < 4; ++nd) oacc[qi][nd] = (f32x4)0.f;
        lacc[qi] = (f32x4)0.f;
    }
    s16x4 vone;
    vone[0] = (short)0x3F80; vone[1] = (short)0x3F80;
    vone[2] = (short)0x3F80; vone[3] = (short)0x3F80;

    // ---- 16 k-slices, NO barriers
#pragma unroll 4
    for (int ki = 0; ki < 16; ++ki) {
        const int krow = ki * 16 + L;                 // 0..255
        const int kxor = (krow & 7) << 4;
        s16x8 ak0 = *(const s16x8*)&smem[LDSK + krow * 128 + ((gq * 16) ^ kxor)];
        s16x8 ak1 = *(const s16x8*)&smem[LDSK + krow * 128 + ((64 + gq * 16) ^ kxor)];

        f32x4 sacc[2];
        __builtin_amdgcn_s_setprio(1);
#pragma unroll
        for (int qi = 0; qi < 2; ++qi) {
            sacc[qi] = __builtin_amdgcn_mfma_f32_16x16x32_bf16(
                ak0, aq[qi][0], (f32x4)0.f, 0, 0, 0);
            sacc[qi] = __builtin_amdgcn_mfma_f32_16x16x32_bf16(
                ak1, aq[qi][1], sacc[qi], 0, 0, 0);
        }
        __builtin_amdgcn_s_setprio(0);

        const int kabs = ki * 16 + gq * 4;            // 0..255, mult of 4
        u32x4 kxy4 = *(const u32x4*)&cxy[kabs];
        u16x4 kz4  = *(const u16x4*)&czs[kabs];

        s16x4 pf[2];
#pragma unroll
        for (int qi = 0; qi < 2; ++qi) {
            float pe[4];
#pragma unroll
            for (int j = 0; j < 4; ++j) {
                unsigned rel = pkmin40(pkmax0(pksub(qxyb[qi], kxy4[j])), c40);
                int ix = (int)(rel & 0xFFFFu);
                int iy = (int)(rel >> 16);
                int iz = qzb[qi] - (int)kz4[j]; iz = iz < 0 ? 0 : (iz > 40 ? 40 : iz);
                float sv = sacc[qi][j] + rpexy[iy * RNUM + ix] + rpez[iz];
                pe[j] = exp2r(sv);
            }
            union { unsigned w[2]; s16x4 v; } u;
            u.w[0] = cvtpk(pe[0], pe[1]);
            u.w[1] = cvtpk(pe[2], pe[3]);
            pf[qi] = u.v;
        }

        const int kblk = (kabs >> 6) * 128;           // 64-col block byte base
        const int koff2 = (kabs & 63) * 2;
        __builtin_amdgcn_s_setprio(1);
#pragma unroll
        for (int qi = 0; qi < 2; ++qi)
            lacc[qi] = __builtin_amdgcn_mfma_f32_16x16x16bf16_1k(
                pf[qi], vone, lacc[qi], 0, 0, 0);
#pragma unroll
        for (int nd = 0; nd < 4; ++nd) {
            int d = nd * 16 + L;
            s16x4 vf = *(const s16x4*)&smem[LDSV + d * 512 + kblk +
                (koff2 ^ ((d & 7) << 4))];
#pragma unroll
            for (int qi = 0; qi < 2; ++qi)
                oacc[qi][nd] = __builtin_amdgcn_mfma_f32_16x16x16bf16_1k(
                    pf[qi], vf, oacc[qi][nd], 0, 0, 0);
        }
        __builtin_amdgcn_s_setprio(0);
    }

    // staging dead; per-wave [16][72] u16 transpose buffer.
    __syncthreads();
    u16* ot = (u16*)&smem[wv * 2304];
#pragma unroll
    for (int qi = 0; qi < 2; ++qi) {
#pragma unroll
        for (int reg = 0; reg < 4; ++reg) {
            float li = 1.f / lacc[qi][reg];
#pragma unroll
            for (int nd = 0; nd < 4; ++nd)
                ot[(gq * 4 + reg) * 72 + nd * 16 + L] = f2b(oacc[qi][nd][reg] * li);
        }
#pragma unroll
        for (int s = 0; s < 4; ++s) {
            int r = s * 4 + (lane >> 4);
            int c = (lane & 15) * 4;
            u16x4 a = *(const u16x4*)&ot[r * 72 + c];
            int q = q0 + qi * 16 + r;
            *(u16x4*)&oa16[(size_t)(p * KP + q) * CCH + h * DH + c] = a;
        }
    }
}

// ---------------------------------------------------------------------------
// Kernel C: proj GEMM: out = A16 @ (Bh+Bl)^T + bias  (frozen)
// ---------------------------------------------------------------------------
__global__ __launch_bounds__(256, 3) void gemm_proj(
    const u16* __restrict__ A16,
    const u16* __restrict__ Bh, const u16* __restrict__ Bl,
    const float* __restrict__ bias, const int* __restrict__ order,
    float* __restrict__ out)
{
    __shared__ __align__(16) unsigned char smemP[49152];   // 48 KB
    u16* LA  = (u16*)smemP;
    u16* LBh = (u16*)&smemP[16384];
    u16* LBl = (u16*)&smemP[32768];

    const int t = threadIdx.x;
    const int lane = t & 63, wv = t >> 6;
    const int L = lane & 15, gq = lane >> 4;
    const int wr = wv >> 1, wc = wv & 1;

    const int orig = blockIdx.y * 3 + blockIdx.x;
    const int swz  = (orig & 7) * 192 + (orig >> 3);        // bijective (1536%8==0)
    const int n0 = (swz % 3) * 128;
    const int m0 = (swz / 3) * 128;

    f32x4 acc[4][4];
#pragma unroll
    for (int mi = 0; mi < 4; ++mi)
#pragma unroll
        for (int ni = 0; ni < 4; ++ni) acc[mi][ni] = (f32x4)0.f;

    for (int kc = 0; kc < K1; kc += 64) {
        __syncthreads();
#pragma unroll
        for (int i = 0; i < 4; ++i) {
            int ci = i * 256 + t;
            int r = ci >> 3, j = ci & 7;
            int c8 = (j ^ (r & 7)) * 8;
            gll16(A16 + (size_t)(m0 + r) * K1 + kc + c8, LA + ci * 8);
            size_t gb = (size_t)(n0 + r) * K1 + kc + c8;
            gll16(Bh + gb, LBh + ci * 8);
            gll16(Bl + gb, LBl + ci * 8);
        }
        __syncthreads();
#pragma unroll
        for (int ks = 0; ks < 2; ++ks) {
            s16x8 fah[4], fbh[4], fbl[4];
#pragma unroll
            for (int x = 0; x < 4; ++x) {
                int arow = wr * 64 + x * 16 + L;
                int brow = wc * 64 + x * 16 + L;
                int ka  = ((ks * 4 + gq) ^ (arow & 7)) * 8;
                int kb2 = ((ks * 4 + gq) ^ (brow & 7)) * 8;
                fah[x] = *(const s16x8*)&LA[arow * 64 + ka];
                fbh[x] = *(const s16x8*)&LBh[brow * 64 + kb2];
                fbl[x] = *(const s16x8*)&LBl[brow * 64 + kb2];
            }
#pragma unroll
            for (int mi = 0; mi < 4; ++mi)
#pragma unroll
                for (int ni = 0; ni < 4; ++ni) {
                    acc[mi][ni] = __builtin_amdgcn_mfma_f32_16x16x32_bf16(
                        fah[mi], fbh[ni], acc[mi][ni], 0, 0, 0);
                    acc[mi][ni] = __builtin_amdgcn_mfma_f32_16x16x32_bf16(
                        fah[mi], fbl[ni], acc[mi][ni], 0, 0, 0);
                }
        }
    }

    float bfrag[4];
#pragma unroll
    for (int ni = 0; ni < 4; ++ni) bfrag[ni] = bias[n0 + wc * 64 + ni * 16 + L];

    __syncthreads();
    float* otp = (float*)smemP + wv * 1088;   // [16][68] f32 per wave
#pragma unroll
    for (int mi = 0; mi < 4; ++mi) {
#pragma unroll
        for (int reg = 0; reg < 4; ++reg)
#pragma unroll
            for (int ni = 0; ni < 4; ++ni)
                otp[(gq * 4 + reg) * 68 + ni * 16 + L] = acc[mi][ni][reg] + bfrag[ni];
#pragma unroll
        for (int s = 0; s < 4; ++s) {
            int r = s * 4 + (lane >> 4);
            int c = (lane & 15) * 4;
            f32x4 a = *(const f32x4*)&otp[r * 68 + c];
            int j = m0 + wr * 64 + mi * 16 + r;
            float* dst = out + (size_t)order[j] * CCH + n0 + wc * 64 + c;
            *(f32x4*)dst = a;
        }
        __syncthreads();
    }
}

// ---------------------------------------------------------------------------
extern "C" void kernel_launch(void* const* d_in, const int* in_sizes, int n_in,
                              void* d_out, int out_size, void* d_ws, size_t ws_size,
                              hipStream_t stream) {
    const float* feat      = (const float*)d_in[0];
    const float* qkv_w     = (const float*)d_in[1];
    const float* qkv_b     = (const float*)d_in[2];
    const float* proj_w    = (const float*)d_in[3];
    const float* proj_b    = (const float*)d_in[4];
    const float* rpe_table = (const float*)d_in[5];
    const int*   order     = (const int*)d_in[6];
    const int*   gcoord    = (const int*)d_in[8];
    float* out = (float*)d_out;

    const size_t NC = (size_t)NPTS * CCH;
    u16* fh   = (u16*)d_ws;
    u16* qwh  = fh + NC;
    u16* pwh  = qwh + (size_t)1152 * 384;
    u16* pwl  = pwh + (size_t)384 * 384;
    u16* qs   = pwl + (size_t)384 * 384;
    u16* ks   = qs + NC;
    u16* vts  = ks + NC;
    u16* oa16 = vts + NC;
    unsigned* cxy_g = (unsigned*)(oa16 + NC);
    u16* cz_g = (u16*)(cxy_g + NPTS);

    cast_bf16<<<(1152 * 384 / 4 + 255) / 256, 256, 0, stream>>>(qkv_w, qwh, 1152 * 384 / 4);
    split_arr<<<(384 * 384 / 4 + 255) / 256, 256, 0, stream>>>(proj_w, pwh, pwl, 384 * 384 / 4);
    gather_h<<<NPTS * 96 / 256, 256, 0, stream>>>(feat, order, fh);
    pack_coords<<<NPTS / 256, 256, 0, stream>>>(order, gcoord, cxy_g, cz_g);

    gemm_qkv<<<dim3(9, NPTS / 128), 256, 0, stream>>>(
        fh, qwh, qkv_b, qs, ks, vts);
    attn_mfma<<<dim3(NPATCH, NH), 512, 0, stream>>>(
        qs, ks, vts, cxy_g, cz_g, rpe_table, oa16);
    gemm_proj<<<dim3(3, NPTS / 128), 256, 0, stream>>>(
        oa16, pwh, pwl, proj_b, order, out);
}

// Round 24
// 222.317 us; speedup vs baseline: 1.0772x; 1.0423x over previous
//
#include <hip/hip_runtime.h>
#include <hip/hip_bf16.h>

// Problem constants
#define NPTS   65536
#define CCH    384
#define NH     6
#define DH     64
#define KP     256   // patch size
#define NPATCH 256   // NPTS / KP
#define PB     20    // POS_BND
#define RNUM   41    // 2*PB+1
#define K1     384   // GEMM inner dim
#define LOG2E  1.44269504088896f

typedef float f32x4 __attribute__((ext_vector_type(4)));
typedef short s16x8 __attribute__((ext_vector_type(8)));
typedef short s16x4 __attribute__((ext_vector_type(4)));
typedef unsigned u32x4 __attribute__((ext_vector_type(4)));
typedef unsigned short u16;
typedef u16 u16x4 __attribute__((ext_vector_type(4)));

static __device__ __forceinline__ u16 f2b(float f) {
    union { __hip_bfloat16 h; u16 u; } cv;
    cv.h = __float2bfloat16(f);
    return cv.u;
}
static __device__ __forceinline__ float b2f(u16 u) {
    union { float f; unsigned v; } cv; cv.v = ((unsigned)u) << 16; return cv.f;
}
static __device__ __forceinline__ void split1(float x, u16& h, u16& l) {
    h = f2b(x);
    l = f2b(x - b2f(h));
}
static __device__ __forceinline__ unsigned cvtpk(float a, float b) {
    unsigned r;
    asm("v_cvt_pk_bf16_f32 %0, %1, %2" : "=v"(r) : "v"(a), "v"(b));
    return r;
}
static __device__ __forceinline__ float exp2r(float x) {
    float r;
    asm("v_exp_f32 %0, %1" : "=v"(r) : "v"(x));
    return r;
}
// packed i16 pair ops (VOP3P)
static __device__ __forceinline__ unsigned pksub(unsigned a, unsigned b) {
    unsigned r;
    asm("v_pk_sub_i16 %0, %1, %2" : "=v"(r) : "v"(a), "v"(b));
    return r;
}
static __device__ __forceinline__ unsigned pkmax0(unsigned a) {
    unsigned r;
    asm("v_pk_max_i16 %0, %1, 0" : "=v"(r) : "v"(a));
    return r;
}
static __device__ __forceinline__ unsigned pkmin40(unsigned a, unsigned c40) {
    unsigned r;
    asm("v_pk_min_i16 %0, %1, %2" : "=v"(r) : "v"(a), "v"(c40));
    return r;
}

typedef __attribute__((address_space(3))) unsigned lds_u;
typedef const __attribute__((address_space(1))) unsigned glob_u;
static __device__ __forceinline__ void gll16(const void* g, void* l) {
    __builtin_amdgcn_global_load_lds((glob_u*)g, (lds_u*)l, 16, 0, 0);
}

// ---------------------------------------------------------------------------
// Merged prep kernel: [gather_h | cast_bf16(qkv_w) | split_arr(proj_w) | coords]
// ---------------------------------------------------------------------------
#define NGATH (NPTS * 96)          // 6291456 (float4s of gathered feat)
#define NCAST (1152 * 384 / 4)     // 110592
#define NSPL  (384 * 384 / 4)      // 36864
#define NPREP (NGATH + NCAST + NSPL + NPTS)

__global__ __launch_bounds__(256) void prep_all(
    const float* __restrict__ feat,  const int* __restrict__ order,
    const int* __restrict__ gcoord,  const float* __restrict__ qkv_w,
    const float* __restrict__ proj_w,
    u16* __restrict__ fh, u16* __restrict__ qwh,
    u16* __restrict__ pwh, u16* __restrict__ pwl,
    unsigned* __restrict__ cxy_g, u16* __restrict__ cz_g)
{
    long gi = (long)blockIdx.x * 256 + threadIdx.x;
    if (gi < NGATH) {
        int i = (int)gi;
        int r = i / 96, c4 = i % 96;
        int o = order[r];
        float4 v = *((const float4*)(feat + (size_t)o * CCH) + c4);
        u16x4 hv;
        hv[0] = f2b(v.x); hv[1] = f2b(v.y); hv[2] = f2b(v.z); hv[3] = f2b(v.w);
        *(u16x4*)&fh[(size_t)r * CCH + c4 * 4] = hv;
    } else if (gi < NGATH + NCAST) {
        int i = (int)(gi - NGATH);
        float4 v = ((const float4*)qkv_w)[i];
        u16x4 hv;
        hv[0] = f2b(v.x); hv[1] = f2b(v.y); hv[2] = f2b(v.z); hv[3] = f2b(v.w);
        *(u16x4*)&qwh[(size_t)i * 4] = hv;
    } else if (gi < NGATH + NCAST + NSPL) {
        int i = (int)(gi - NGATH - NCAST);
        float4 v = ((const float4*)proj_w)[i];
        u16 h0, l0, h1, l1, h2, l2, h3, l3;
        split1(v.x, h0, l0); split1(v.y, h1, l1);
        split1(v.z, h2, l2); split1(v.w, h3, l3);
        u16x4 hv, lv;
        hv[0] = h0; hv[1] = h1; hv[2] = h2; hv[3] = h3;
        lv[0] = l0; lv[1] = l1; lv[2] = l2; lv[3] = l3;
        *(u16x4*)&pwh[(size_t)i * 4] = hv;
        *(u16x4*)&pwl[(size_t)i * 4] = lv;
    } else if (gi < NPREP) {
        int j = (int)(gi - NGATH - NCAST - NSPL);
        int o = order[j];
        const int* gc = gcoord + (size_t)o * 3;
        cxy_g[j] = (unsigned)gc[0] | ((unsigned)gc[1] << 16);
        cz_g[j]  = (u16)gc[2];
    }
}

// ---------------------------------------------------------------------------
// Kernel A: 1-term bf16 GEMM (qkv): C = Ah*Bh  (frozen)
// ---------------------------------------------------------------------------
__global__ __launch_bounds__(256, 4) void gemm_qkv(
    const u16* __restrict__ Ah, const u16* __restrict__ Bh,
    const float* __restrict__ bias,
    u16* __restrict__ q_out, u16* __restrict__ k_out, u16* __restrict__ vt_out)
{
    __shared__ __align__(16) u16 lds[2 * 128 * 64];   // 32 KB
    u16* LAh = lds;
    u16* LBh = lds + 128 * 64;

    const int t = threadIdx.x;
    const int lane = t & 63, wv = t >> 6;
    const int L = lane & 15, gq = lane >> 4;
    const int wr = wv >> 1, wc = wv & 1;

    const int orig = blockIdx.y * 9 + blockIdx.x;
    const int swz  = (orig & 7) * 576 + (orig >> 3);        // bijective (4608%8==0)
    const int n0 = (swz % 9) * 128;
    const int m0 = (swz / 9) * 128;

    f32x4 acc[4][4];
#pragma unroll
    for (int mi = 0; mi < 4; ++mi)
#pragma unroll
        for (int ni = 0; ni < 4; ++ni) acc[mi][ni] = (f32x4)0.f;

    for (int kc = 0; kc < K1; kc += 64) {
        __syncthreads();
#pragma unroll
        for (int i = 0; i < 4; ++i) {
            int ci = i * 256 + t;
            int r = ci >> 3, j = ci & 7;
            int c8 = (j ^ (r & 7)) * 8;
            gll16(Ah + (size_t)(m0 + r) * K1 + kc + c8, LAh + ci * 8);
            gll16(Bh + (size_t)(n0 + r) * K1 + kc + c8, LBh + ci * 8);
        }
        __syncthreads();
#pragma unroll
        for (int ks = 0; ks < 2; ++ks) {
            s16x8 fah[4], fbh[4];
#pragma unroll
            for (int x = 0; x < 4; ++x) {
                int arow = wr * 64 + x * 16 + L;
                int brow = wc * 64 + x * 16 + L;
                int ka  = ((ks * 4 + gq) ^ (arow & 7)) * 8;
                int kb2 = ((ks * 4 + gq) ^ (brow & 7)) * 8;
                fah[x] = *(const s16x8*)&LAh[arow * 64 + ka];
                fbh[x] = *(const s16x8*)&LBh[brow * 64 + kb2];
            }
#pragma unroll
            for (int mi = 0; mi < 4; ++mi)
#pragma unroll
                for (int ni = 0; ni < 4; ++ni)
                    acc[mi][ni] = __builtin_amdgcn_mfma_f32_16x16x32_bf16(
                        fah[mi], fbh[ni], acc[mi][ni], 0, 0, 0);
        }
    }

    float bfrag[4];
#pragma unroll
    for (int ni = 0; ni < 4; ++ni) bfrag[ni] = bias[n0 + wc * 64 + ni * 16 + L];

    const int cq   = n0 + wc * 64;
    const int ssel = cq / CCH;
    const int hh   = (cq % CCH) / DH;

    if (ssel == 2) {
#pragma unroll
        for (int mi = 0; mi < 4; ++mi) {
            int jb = m0 + wr * 64 + mi * 16;
            int p = jb >> 8, kr0 = (jb & 255) + gq * 4;
            size_t hb = (size_t)(p * NH + hh) * DH;
#pragma unroll
            for (int ni = 0; ni < 4; ++ni) {
                int d = ni * 16 + L;
                u16x4 w;
#pragma unroll
                for (int reg = 0; reg < 4; ++reg)
                    w[reg] = f2b(acc[mi][ni][reg] + bfrag[ni]);
                int kswz = (kr0 & ~63) + ((kr0 & 63) ^ ((d & 7) << 3));
                *(u16x4*)&vt_out[(hb + d) * KP + kswz] = w;
            }
        }
    } else if (ssel == 1) {
#pragma unroll
        for (int mi = 0; mi < 4; ++mi)
#pragma unroll
            for (int reg = 0; reg < 4; ++reg) {
                int j = m0 + wr * 64 + mi * 16 + gq * 4 + reg;
                int kk = j & 255;
                u16* orow = k_out + ((size_t)((j >> 8) * NH + hh) * KP + kk) * DH;
                int sw = (kk & 7) << 3;
#pragma unroll
                for (int ni = 0; ni < 4; ++ni)
                    orow[(ni * 16 + L) ^ sw] = f2b(acc[mi][ni][reg] + bfrag[ni]);
            }
    } else {
        const float qscl = 0.125f * LOG2E;
#pragma unroll
        for (int mi = 0; mi < 4; ++mi)
#pragma unroll
            for (int reg = 0; reg < 4; ++reg) {
                int j = m0 + wr * 64 + mi * 16 + gq * 4 + reg;
                u16* orow = q_out + ((size_t)((j >> 8) * NH + hh) * KP + (j & 255)) * DH;
#pragma unroll
                for (int ni = 0; ni < 4; ++ni)
                    orow[ni * 16 + L] = f2b((acc[mi][ni][reg] + bfrag[ni]) * qscl);
            }
    }
}

// ---------------------------------------------------------------------------
// Kernel B: swapped-operand MFMA flash attention per (patch, head).
// Whole K/V^T staged once; zero-barrier 16-slice k-loop; exp2 softmax;
// MFMA ones-column row-sum; packed-i16 coord clamps. (frozen from R23)
// ---------------------------------------------------------------------------
#define LDSK  0                      // 256 rows x 128 B = 32768
#define LDSV  32768                  // 64 d-rows x 512 B = 32768
#define CXYO  65536                  // 256 u32 = 1024
#define CZO   66560                  // 256 u16 = 512
#define RPEXY 67072                  // 1681 f32 = 6724 (pad 6784)
#define RPEZ  73856                  // 41 f32
#define SMEMSZ 74048

__global__ __launch_bounds__(512, 2) void attn_mfma(
    const u16* __restrict__ q_s, const u16* __restrict__ k_s,
    const u16* __restrict__ vt_s, const unsigned* __restrict__ cxy_g,
    const u16* __restrict__ cz_g,
    const float* __restrict__ rpe_table, u16* __restrict__ oa16)
{
    __shared__ __align__(16) unsigned char smem[SMEMSZ];
    unsigned* cxy   = (unsigned*)&smem[CXYO];
    u16*      czs   = (u16*)&smem[CZO];
    float*    rpexy = (float*)&smem[RPEXY];
    float*    rpez  = (float*)&smem[RPEZ];

    const int t    = threadIdx.x;
    const int p    = blockIdx.x, h = blockIdx.y;
    const int lane = t & 63, wv = t >> 6;
    const int L    = lane & 15, gq = lane >> 4;
    const int q0   = wv * 32;
    const size_t base = (size_t)(p * NH + h) * KP * DH;

    // ---- stage EVERYTHING once: K (2048 chunks), V^T (2048 chunks)
#pragma unroll
    for (int i = 0; i < 4; ++i) {
        int ci = i * 512 + t;
        int r = ci >> 3, j = ci & 7;            // K row, chunk
        gll16(k_s + base + (size_t)r * DH + j * 8, &smem[LDSK + ci * 16]);
        int d = ci >> 5, jc = ci & 31;          // V d-row, chunk
        gll16(vt_s + base + (size_t)d * KP + jc * 8, &smem[LDSV + ci * 16]);
    }
    if (t < KP) {
        cxy[t] = cxy_g[p * KP + t];
        czs[t] = cz_g[p * KP + t];
    }
    for (int idx = t; idx < RNUM * RNUM; idx += 512) {
        int ix = idx % RNUM, iy = idx / RNUM;
        rpexy[idx] = (rpe_table[ix * NH + h] + rpe_table[(RNUM + iy) * NH + h]) * LOG2E;
    }
    if (t < RNUM) rpez[t] = rpe_table[(2 * RNUM + t) * NH + h] * LOG2E;
    __syncthreads();

    unsigned qxyb[2];
    int qzb[2];
    const unsigned c40 = 0x00280028u;
#pragma unroll
    for (int qi = 0; qi < 2; ++qi) {
        qxyb[qi] = cxy[q0 + qi * 16 + L] + 0x00140014u;
        qzb[qi]  = (int)czs[q0 + qi * 16 + L] + PB;
    }

    s16x8 aq[2][2];
#pragma unroll
    for (int qi = 0; qi < 2; ++qi)
#pragma unroll
        for (int ks = 0; ks < 2; ++ks)
            aq[qi][ks] = *(const s16x8*)&q_s[base +
                (size_t)(q0 + qi * 16 + L) * DH + ks * 32 + gq * 8];

    f32x4 oacc[2][4];
    f32x4 lacc[2];
#pragma unroll
    for (int qi = 0; qi < 2; ++qi) {
#pragma unroll
        for (int nd = 0; nd < 4; ++nd) oacc[qi][nd] = (f32x4)0.f;
        lacc[qi] = (f32x4)0.f;
    }
    s16x4 vone;
    vone[0] = (short)0x3F80; vone[1] = (short)0x3F80;
    vone[2] = (short)0x3F80; vone[3] = (short)0x3F80;

    // ---- 16 k-slices, no barriers
#pragma unroll 4
    for (int ki = 0; ki < 16; ++ki) {
        const int krow = ki * 16 + L;
        const int kxor = (krow & 7) << 4;
        s16x8 ak0 = *(const s16x8*)&smem[LDSK + krow * 128 + ((gq * 16) ^ kxor)];
        s16x8 ak1 = *(const s16x8*)&smem[LDSK + krow * 128 + ((64 + gq * 16) ^ kxor)];

        f32x4 sacc[2];
        __builtin_amdgcn_s_setprio(1);
#pragma unroll
        for (int qi = 0; qi < 2; ++qi) {
            sacc[qi] = __builtin_amdgcn_mfma_f32_16x16x32_bf16(
                ak0, aq[qi][0], (f32x4)0.f, 0, 0, 0);
            sacc[qi] = __builtin_amdgcn_mfma_f32_16x16x32_bf16(
                ak1, aq[qi][1], sacc[qi], 0, 0, 0);
        }
        __builtin_amdgcn_s_setprio(0);

        const int kabs = ki * 16 + gq * 4;
        u32x4 kxy4 = *(const u32x4*)&cxy[kabs];
        u16x4 kz4  = *(const u16x4*)&czs[kabs];

        s16x4 pf[2];
#pragma unroll
        for (int qi = 0; qi < 2; ++qi) {
            float pe[4];
#pragma unroll
            for (int j = 0; j < 4; ++j) {
                unsigned rel = pkmin40(pkmax0(pksub(qxyb[qi], kxy4[j])), c40);
                int ix = (int)(rel & 0xFFFFu);
                int iy = (int)(rel >> 16);
                int iz = qzb[qi] - (int)kz4[j]; iz = iz < 0 ? 0 : (iz > 40 ? 40 : iz);
                float sv = sacc[qi][j] + rpexy[iy * RNUM + ix] + rpez[iz];
                pe[j] = exp2r(sv);
            }
            union { unsigned w[2]; s16x4 v; } u;
            u.w[0] = cvtpk(pe[0], pe[1]);
            u.w[1] = cvtpk(pe[2], pe[3]);
            pf[qi] = u.v;
        }

        const int kblk = (kabs >> 6) * 128;
        const int koff2 = (kabs & 63) * 2;
        __builtin_amdgcn_s_setprio(1);
#pragma unroll
        for (int qi = 0; qi < 2; ++qi)
            lacc[qi] = __builtin_amdgcn_mfma_f32_16x16x16bf16_1k(
                pf[qi], vone, lacc[qi], 0, 0, 0);
#pragma unroll
        for (int nd = 0; nd < 4; ++nd) {
            int d = nd * 16 + L;
            s16x4 vf = *(const s16x4*)&smem[LDSV + d * 512 + kblk +
                (koff2 ^ ((d & 7) << 4))];
#pragma unroll
            for (int qi = 0; qi < 2; ++qi)
                oacc[qi][nd] = __builtin_amdgcn_mfma_f32_16x16x16bf16_1k(
                    pf[qi], vf, oacc[qi][nd], 0, 0, 0);
        }
        __builtin_amdgcn_s_setprio(0);
    }

    // staging dead; per-wave [16][72] u16 transpose buffer.
    __syncthreads();
    u16* ot = (u16*)&smem[wv * 2304];
#pragma unroll
    for (int qi = 0; qi < 2; ++qi) {
#pragma unroll
        for (int reg = 0; reg < 4; ++reg) {
            float li = 1.f / lacc[qi][reg];
#pragma unroll
            for (int nd = 0; nd < 4; ++nd)
                ot[(gq * 4 + reg) * 72 + nd * 16 + L] = f2b(oacc[qi][nd][reg] * li);
        }
#pragma unroll
        for (int s = 0; s < 4; ++s) {
            int r = s * 4 + (lane >> 4);
            int c = (lane & 15) * 4;
            u16x4 a = *(const u16x4*)&ot[r * 72 + c];
            int q = q0 + qi * 16 + r;
            *(u16x4*)&oa16[(size_t)(p * KP + q) * CCH + h * DH + c] = a;
        }
    }
}

// ---------------------------------------------------------------------------
// Kernel C: proj GEMM: out = A16 @ (Bh+Bl)^T + bias  (frozen)
// ---------------------------------------------------------------------------
__global__ __launch_bounds__(256, 3) void gemm_proj(
    const u16* __restrict__ A16,
    const u16* __restrict__ Bh, const u16* __restrict__ Bl,
    const float* __restrict__ bias, const int* __restrict__ order,
    float* __restrict__ out)
{
    __shared__ __align__(16) unsigned char smemP[49152];   // 48 KB
    u16* LA  = (u16*)smemP;
    u16* LBh = (u16*)&smemP[16384];
    u16* LBl = (u16*)&smemP[32768];

    const int t = threadIdx.x;
    const int lane = t & 63, wv = t >> 6;
    const int L = lane & 15, gq = lane >> 4;
    const int wr = wv >> 1, wc = wv & 1;

    const int orig = blockIdx.y * 3 + blockIdx.x;
    const int swz  = (orig & 7) * 192 + (orig >> 3);        // bijective (1536%8==0)
    const int n0 = (swz % 3) * 128;
    const int m0 = (swz / 3) * 128;

    f32x4 acc[4][4];
#pragma unroll
    for (int mi = 0; mi < 4; ++mi)
#pragma unroll
        for (int ni = 0; ni < 4; ++ni) acc[mi][ni] = (f32x4)0.f;

    for (int kc = 0; kc < K1; kc += 64) {
        __syncthreads();
#pragma unroll
        for (int i = 0; i < 4; ++i) {
            int ci = i * 256 + t;
            int r = ci >> 3, j = ci & 7;
            int c8 = (j ^ (r & 7)) * 8;
            gll16(A16 + (size_t)(m0 + r) * K1 + kc + c8, LA + ci * 8);
            size_t gb = (size_t)(n0 + r) * K1 + kc + c8;
            gll16(Bh + gb, LBh + ci * 8);
            gll16(Bl + gb, LBl + ci * 8);
        }
        __syncthreads();
#pragma unroll
        for (int ks = 0; ks < 2; ++ks) {
            s16x8 fah[4], fbh[4], fbl[4];
#pragma unroll
            for (int x = 0; x < 4; ++x) {
                int arow = wr * 64 + x * 16 + L;
                int brow = wc * 64 + x * 16 + L;
                int ka  = ((ks * 4 + gq) ^ (arow & 7)) * 8;
                int kb2 = ((ks * 4 + gq) ^ (brow & 7)) * 8;
                fah[x] = *(const s16x8*)&LA[arow * 64 + ka];
                fbh[x] = *(const s16x8*)&LBh[brow * 64 + kb2];
                fbl[x] = *(const s16x8*)&LBl[brow * 64 + kb2];
            }
#pragma unroll
            for (int mi = 0; mi < 4; ++mi)
#pragma unroll
                for (int ni = 0; ni < 4; ++ni) {
                    acc[mi][ni] = __builtin_amdgcn_mfma_f32_16x16x32_bf16(
                        fah[mi], fbh[ni], acc[mi][ni], 0, 0, 0);
                    acc[mi][ni] = __builtin_amdgcn_mfma_f32_16x16x32_bf16(
                        fah[mi], fbl[ni], acc[mi][ni], 0, 0, 0);
                }
        }
    }

    float bfrag[4];
#pragma unroll
    for (int ni = 0; ni < 4; ++ni) bfrag[ni] = bias[n0 + wc * 64 + ni * 16 + L];

    __syncthreads();
    float* otp = (float*)smemP + wv * 1088;   // [16][68] f32 per wave
#pragma unroll
    for (int mi = 0; mi < 4; ++mi) {
#pragma unroll
        for (int reg = 0; reg < 4; ++reg)
#pragma unroll
            for (int ni = 0; ni < 4; ++ni)
                otp[(gq * 4 + reg) * 68 + ni * 16 + L] = acc[mi][ni][reg] + bfrag[ni];
#pragma unroll
        for (int s = 0; s < 4; ++s) {
            int r = s * 4 + (lane >> 4);
            int c = (lane & 15) * 4;
            f32x4 a = *(const f32x4*)&otp[r * 68 + c];
            int j = m0 + wr * 64 + mi * 16 + r;
            float* dst = out + (size_t)order[j] * CCH + n0 + wc * 64 + c;
            *(f32x4*)dst = a;
        }
        __syncthreads();
    }
}

// ---------------------------------------------------------------------------
extern "C" void kernel_launch(void* const* d_in, const int* in_sizes, int n_in,
                              void* d_out, int out_size, void* d_ws, size_t ws_size,
                              hipStream_t stream) {
    const float* feat      = (const float*)d_in[0];
    const float* qkv_w     = (const float*)d_in[1];
    const float* qkv_b     = (const float*)d_in[2];
    const float* proj_w    = (const float*)d_in[3];
    const float* proj_b    = (const float*)d_in[4];
    const float* rpe_table = (const float*)d_in[5];
    const int*   order     = (const int*)d_in[6];
    const int*   gcoord    = (const int*)d_in[8];
    float* out = (float*)d_out;

    const size_t NC = (size_t)NPTS * CCH;
    u16* fh   = (u16*)d_ws;
    u16* qwh  = fh + NC;
    u16* pwh  = qwh + (size_t)1152 * 384;
    u16* pwl  = pwh + (size_t)384 * 384;
    u16* qs   = pwl + (size_t)384 * 384;
    u16* ks   = qs + NC;
    u16* vts  = ks + NC;
    u16* oa16 = vts + NC;
    unsigned* cxy_g = (unsigned*)(oa16 + NC);
    u16* cz_g = (u16*)(cxy_g + NPTS);

    prep_all<<<(NPREP + 255) / 256, 256, 0, stream>>>(
        feat, order, gcoord, qkv_w, proj_w,
        fh, qwh, pwh, pwl, cxy_g, cz_g);

    gemm_qkv<<<dim3(9, NPTS / 128), 256, 0, stream>>>(
        fh, qwh, qkv_b, qs, ks, vts);
    attn_mfma<<<dim3(NPATCH, NH), 512, 0, stream>>>(
        qs, ks, vts, cxy_g, cz_g, rpe_table, oa16);
    gemm_proj<<<dim3(3, NPTS / 128), 256, 0, stream>>>(
        oa16, pwh, pwl, proj_b, order, out);
}

// Round 25
// 220.961 us; speedup vs baseline: 1.0838x; 1.0061x over previous
//
#include <hip/hip_runtime.h>
#include <hip/hip_bf16.h>

// Problem constants
#define NPTS   65536
#define CCH    384
#define NH     6
#define DH     64
#define KP     256   // patch size
#define NPATCH 256   // NPTS / KP
#define PB     20    // POS_BND
#define RNUM   41    // 2*PB+1
#define K1     384   // GEMM inner dim
#define LOG2E  1.44269504088896f

typedef float f32x4 __attribute__((ext_vector_type(4)));
typedef short s16x8 __attribute__((ext_vector_type(8)));
typedef short s16x4 __attribute__((ext_vector_type(4)));
typedef unsigned u32x4 __attribute__((ext_vector_type(4)));
typedef unsigned short u16;
typedef u16 u16x4 __attribute__((ext_vector_type(4)));

static __device__ __forceinline__ u16 f2b(float f) {
    union { __hip_bfloat16 h; u16 u; } cv;
    cv.h = __float2bfloat16(f);
    return cv.u;
}
static __device__ __forceinline__ float b2f(u16 u) {
    union { float f; unsigned v; } cv; cv.v = ((unsigned)u) << 16; return cv.f;
}
static __device__ __forceinline__ void split1(float x, u16& h, u16& l) {
    h = f2b(x);
    l = f2b(x - b2f(h));
}
static __device__ __forceinline__ unsigned cvtpk(float a, float b) {
    unsigned r;
    asm("v_cvt_pk_bf16_f32 %0, %1, %2" : "=v"(r) : "v"(a), "v"(b));
    return r;
}
static __device__ __forceinline__ float exp2r(float x) {
    float r;
    asm("v_exp_f32 %0, %1" : "=v"(r) : "v"(x));
    return r;
}
static __device__ __forceinline__ float rcpr(float x) {
    float r;
    asm("v_rcp_f32 %0, %1" : "=v"(r) : "v"(x));
    return r;
}
// packed i16 pair ops (VOP3P)
static __device__ __forceinline__ unsigned pksub(unsigned a, unsigned b) {
    unsigned r;
    asm("v_pk_sub_i16 %0, %1, %2" : "=v"(r) : "v"(a), "v"(b));
    return r;
}
static __device__ __forceinline__ unsigned pkmax0(unsigned a) {
    unsigned r;
    asm("v_pk_max_i16 %0, %1, 0" : "=v"(r) : "v"(a));
    return r;
}
static __device__ __forceinline__ unsigned pkmin40(unsigned a, unsigned c40) {
    unsigned r;
    asm("v_pk_min_i16 %0, %1, %2" : "=v"(r) : "v"(a), "v"(c40));
    return r;
}

typedef __attribute__((address_space(3))) unsigned lds_u;
typedef const __attribute__((address_space(1))) unsigned glob_u;
static __device__ __forceinline__ void gll16(const void* g, void* l) {
    __builtin_amdgcn_global_load_lds((glob_u*)g, (lds_u*)l, 16, 0, 0);
}

// ---------------------------------------------------------------------------
// Merged prep kernel: [gather_h | cast_bf16(qkv_w) | split_arr(proj_w) | coords]
// ---------------------------------------------------------------------------
#define NGATH (NPTS * 96)          // 6291456 (float4s of gathered feat)
#define NCAST (1152 * 384 / 4)     // 110592
#define NSPL  (384 * 384 / 4)      // 36864
#define NPREP (NGATH + NCAST + NSPL + NPTS)

__global__ __launch_bounds__(256) void prep_all(
    const float* __restrict__ feat,  const int* __restrict__ order,
    const int* __restrict__ gcoord,  const float* __restrict__ qkv_w,
    const float* __restrict__ proj_w,
    u16* __restrict__ fh, u16* __restrict__ qwh,
    u16* __restrict__ pwh, u16* __restrict__ pwl,
    unsigned* __restrict__ cxy_g, u16* __restrict__ cz_g)
{
    long gi = (long)blockIdx.x * 256 + threadIdx.x;
    if (gi < NGATH) {
        int i = (int)gi;
        int r = i / 96, c4 = i % 96;
        int o = order[r];
        float4 v = *((const float4*)(feat + (size_t)o * CCH) + c4);
        u16x4 hv;
        hv[0] = f2b(v.x); hv[1] = f2b(v.y); hv[2] = f2b(v.z); hv[3] = f2b(v.w);
        *(u16x4*)&fh[(size_t)r * CCH + c4 * 4] = hv;
    } else if (gi < NGATH + NCAST) {
        int i = (int)(gi - NGATH);
        float4 v = ((const float4*)qkv_w)[i];
        u16x4 hv;
        hv[0] = f2b(v.x); hv[1] = f2b(v.y); hv[2] = f2b(v.z); hv[3] = f2b(v.w);
        *(u16x4*)&qwh[(size_t)i * 4] = hv;
    } else if (gi < NGATH + NCAST + NSPL) {
        int i = (int)(gi - NGATH - NCAST);
        float4 v = ((const float4*)proj_w)[i];
        u16 h0, l0, h1, l1, h2, l2, h3, l3;
        split1(v.x, h0, l0); split1(v.y, h1, l1);
        split1(v.z, h2, l2); split1(v.w, h3, l3);
        u16x4 hv, lv;
        hv[0] = h0; hv[1] = h1; hv[2] = h2; hv[3] = h3;
        lv[0] = l0; lv[1] = l1; lv[2] = l2; lv[3] = l3;
        *(u16x4*)&pwh[(size_t)i * 4] = hv;
        *(u16x4*)&pwl[(size_t)i * 4] = lv;
    } else if (gi < NPREP) {
        int j = (int)(gi - NGATH - NCAST - NSPL);
        int o = order[j];
        const int* gc = gcoord + (size_t)o * 3;
        cxy_g[j] = (unsigned)gc[0] | ((unsigned)gc[1] << 16);
        cz_g[j]  = (u16)gc[2];
    }
}

// ---------------------------------------------------------------------------
// Kernel A: 1-term bf16 GEMM (qkv): C = Ah*Bh  (frozen)
// ---------------------------------------------------------------------------
__global__ __launch_bounds__(256, 4) void gemm_qkv(
    const u16* __restrict__ Ah, const u16* __restrict__ Bh,
    const float* __restrict__ bias,
    u16* __restrict__ q_out, u16* __restrict__ k_out, u16* __restrict__ vt_out)
{
    __shared__ __align__(16) u16 lds[2 * 128 * 64];   // 32 KB
    u16* LAh = lds;
    u16* LBh = lds + 128 * 64;

    const int t = threadIdx.x;
    const int lane = t & 63, wv = t >> 6;
    const int L = lane & 15, gq = lane >> 4;
    const int wr = wv >> 1, wc = wv & 1;

    const int orig = blockIdx.y * 9 + blockIdx.x;
    const int swz  = (orig & 7) * 576 + (orig >> 3);        // bijective (4608%8==0)
    const int n0 = (swz % 9) * 128;
    const int m0 = (swz / 9) * 128;

    f32x4 acc[4][4];
#pragma unroll
    for (int mi = 0; mi < 4; ++mi)
#pragma unroll
        for (int ni = 0; ni < 4; ++ni) acc[mi][ni] = (f32x4)0.f;

    for (int kc = 0; kc < K1; kc += 64) {
        __syncthreads();
#pragma unroll
        for (int i = 0; i < 4; ++i) {
            int ci = i * 256 + t;
            int r = ci >> 3, j = ci & 7;
            int c8 = (j ^ (r & 7)) * 8;
            gll16(Ah + (size_t)(m0 + r) * K1 + kc + c8, LAh + ci * 8);
            gll16(Bh + (size_t)(n0 + r) * K1 + kc + c8, LBh + ci * 8);
        }
        __syncthreads();
#pragma unroll
        for (int ks = 0; ks < 2; ++ks) {
            s16x8 fah[4], fbh[4];
#pragma unroll
            for (int x = 0; x < 4; ++x) {
                int arow = wr * 64 + x * 16 + L;
                int brow = wc * 64 + x * 16 + L;
                int ka  = ((ks * 4 + gq) ^ (arow & 7)) * 8;
                int kb2 = ((ks * 4 + gq) ^ (brow & 7)) * 8;
                fah[x] = *(const s16x8*)&LAh[arow * 64 + ka];
                fbh[x] = *(const s16x8*)&LBh[brow * 64 + kb2];
            }
#pragma unroll
            for (int mi = 0; mi < 4; ++mi)
#pragma unroll
                for (int ni = 0; ni < 4; ++ni)
                    acc[mi][ni] = __builtin_amdgcn_mfma_f32_16x16x32_bf16(
                        fah[mi], fbh[ni], acc[mi][ni], 0, 0, 0);
        }
    }

    float bfrag[4];
#pragma unroll
    for (int ni = 0; ni < 4; ++ni) bfrag[ni] = bias[n0 + wc * 64 + ni * 16 + L];

    const int cq   = n0 + wc * 64;
    const int ssel = cq / CCH;
    const int hh   = (cq % CCH) / DH;

    if (ssel == 2) {
#pragma unroll
        for (int mi = 0; mi < 4; ++mi) {
            int jb = m0 + wr * 64 + mi * 16;
            int p = jb >> 8, kr0 = (jb & 255) + gq * 4;
            size_t hb = (size_t)(p * NH + hh) * DH;
#pragma unroll
            for (int ni = 0; ni < 4; ++ni) {
                int d = ni * 16 + L;
                u16x4 w;
#pragma unroll
                for (int reg = 0; reg < 4; ++reg)
                    w[reg] = f2b(acc[mi][ni][reg] + bfrag[ni]);
                int kswz = (kr0 & ~63) + ((kr0 & 63) ^ ((d & 7) << 3));
                *(u16x4*)&vt_out[(hb + d) * KP + kswz] = w;
            }
        }
    } else if (ssel == 1) {
#pragma unroll
        for (int mi = 0; mi < 4; ++mi)
#pragma unroll
            for (int reg = 0; reg < 4; ++reg) {
                int j = m0 + wr * 64 + mi * 16 + gq * 4 + reg;
                int kk = j & 255;
                u16* orow = k_out + ((size_t)((j >> 8) * NH + hh) * KP + kk) * DH;
                int sw = (kk & 7) << 3;
#pragma unroll
                for (int ni = 0; ni < 4; ++ni)
                    orow[(ni * 16 + L) ^ sw] = f2b(acc[mi][ni][reg] + bfrag[ni]);
            }
    } else {
        const float qscl = 0.125f * LOG2E;
#pragma unroll
        for (int mi = 0; mi < 4; ++mi)
#pragma unroll
            for (int reg = 0; reg < 4; ++reg) {
                int j = m0 + wr * 64 + mi * 16 + gq * 4 + reg;
                u16* orow = q_out + ((size_t)((j >> 8) * NH + hh) * KP + (j & 255)) * DH;
#pragma unroll
                for (int ni = 0; ni < 4; ++ni)
                    orow[ni * 16 + L] = f2b((acc[mi][ni][reg] + bfrag[ni]) * qscl);
            }
    }
}

// ---------------------------------------------------------------------------
// Kernel B: swapped-operand MFMA flash attention per (patch, head).
// Whole K/V^T staged once; FULLY UNROLLED zero-barrier 16-slice k-loop
// (cross-slice software pipelining); exp2 softmax; MFMA ones-column row-sum;
// packed-i16 coord clamps; v_rcp epilogue.
// ---------------------------------------------------------------------------
#define LDSK  0                      // 256 rows x 128 B = 32768
#define LDSV  32768                  // 64 d-rows x 512 B = 32768
#define CXYO  65536                  // 256 u32 = 1024
#define CZO   66560                  // 256 u16 = 512
#define RPEXY 67072                  // 1681 f32 = 6724 (pad 6784)
#define RPEZ  73856                  // 41 f32
#define SMEMSZ 74048

__global__ __launch_bounds__(512, 2) void attn_mfma(
    const u16* __restrict__ q_s, const u16* __restrict__ k_s,
    const u16* __restrict__ vt_s, const unsigned* __restrict__ cxy_g,
    const u16* __restrict__ cz_g,
    const float* __restrict__ rpe_table, u16* __restrict__ oa16)
{
    __shared__ __align__(16) unsigned char smem[SMEMSZ];
    unsigned* cxy   = (unsigned*)&smem[CXYO];
    u16*      czs   = (u16*)&smem[CZO];
    float*    rpexy = (float*)&smem[RPEXY];
    float*    rpez  = (float*)&smem[RPEZ];

    const int t    = threadIdx.x;
    const int p    = blockIdx.x, h = blockIdx.y;
    const int lane = t & 63, wv = t >> 6;
    const int L    = lane & 15, gq = lane >> 4;
    const int q0   = wv * 32;
    const size_t base = (size_t)(p * NH + h) * KP * DH;

    // ---- stage EVERYTHING once: K (2048 chunks), V^T (2048 chunks)
#pragma unroll
    for (int i = 0; i < 4; ++i) {
        int ci = i * 512 + t;
        int r = ci >> 3, j = ci & 7;            // K row, chunk
        gll16(k_s + base + (size_t)r * DH + j * 8, &smem[LDSK + ci * 16]);
        int d = ci >> 5, jc = ci & 31;          // V d-row, chunk
        gll16(vt_s + base + (size_t)d * KP + jc * 8, &smem[LDSV + ci * 16]);
    }
    if (t < KP) {
        cxy[t] = cxy_g[p * KP + t];
        czs[t] = cz_g[p * KP + t];
    }
    for (int idx = t; idx < RNUM * RNUM; idx += 512) {
        int ix = idx % RNUM, iy = idx / RNUM;
        rpexy[idx] = (rpe_table[ix * NH + h] + rpe_table[(RNUM + iy) * NH + h]) * LOG2E;
    }
    if (t < RNUM) rpez[t] = rpe_table[(2 * RNUM + t) * NH + h] * LOG2E;
    __syncthreads();

    unsigned qxyb[2];
    int qzb[2];
    const unsigned c40 = 0x00280028u;
#pragma unroll
    for (int qi = 0; qi < 2; ++qi) {
        qxyb[qi] = cxy[q0 + qi * 16 + L] + 0x00140014u;
        qzb[qi]  = (int)czs[q0 + qi * 16 + L] + PB;
    }

    s16x8 aq[2][2];
#pragma unroll
    for (int qi = 0; qi < 2; ++qi)
#pragma unroll
        for (int ks = 0; ks < 2; ++ks)
            aq[qi][ks] = *(const s16x8*)&q_s[base +
                (size_t)(q0 + qi * 16 + L) * DH + ks * 32 + gq * 8];

    f32x4 oacc[2][4];
    f32x4 lacc[2];
#pragma unroll
    for (int qi = 0; qi < 2; ++qi) {
#pragma unroll
        for (int nd = 0; nd < 4; ++nd) oacc[qi][nd] = (f32x4)0.f;
        lacc[qi] = (f32x4)0.f;
    }
    s16x4 vone;
    vone[0] = (short)0x3F80; vone[1] = (short)0x3F80;
    vone[2] = (short)0x3F80; vone[3] = (short)0x3F80;

    // ---- 16 k-slices, no barriers, FULL unroll (cross-slice pipelining)
#pragma unroll
    for (int ki = 0; ki < 16; ++ki) {
        const int krow = ki * 16 + L;
        const int kxor = (krow & 7) << 4;
        s16x8 ak0 = *(const s16x8*)&smem[LDSK + krow * 128 + ((gq * 16) ^ kxor)];
        s16x8 ak1 = *(const s16x8*)&smem[LDSK + krow * 128 + ((64 + gq * 16) ^ kxor)];

        f32x4 sacc[2];
        __builtin_amdgcn_s_setprio(1);
#pragma unroll
        for (int qi = 0; qi < 2; ++qi) {
            sacc[qi] = __builtin_amdgcn_mfma_f32_16x16x32_bf16(
                ak0, aq[qi][0], (f32x4)0.f, 0, 0, 0);
            sacc[qi] = __builtin_amdgcn_mfma_f32_16x16x32_bf16(
                ak1, aq[qi][1], sacc[qi], 0, 0, 0);
        }
        __builtin_amdgcn_s_setprio(0);

        const int kabs = ki * 16 + gq * 4;
        u32x4 kxy4 = *(const u32x4*)&cxy[kabs];
        u16x4 kz4  = *(const u16x4*)&czs[kabs];

        s16x4 pf[2];
#pragma unroll
        for (int qi = 0; qi < 2; ++qi) {
            float pe[4];
#pragma unroll
            for (int j = 0; j < 4; ++j) {
                unsigned rel = pkmin40(pkmax0(pksub(qxyb[qi], kxy4[j])), c40);
                int ix = (int)(rel & 0xFFFFu);
                int iy = (int)(rel >> 16);
                int iz = qzb[qi] - (int)kz4[j]; iz = iz < 0 ? 0 : (iz > 40 ? 40 : iz);
                float sv = sacc[qi][j] + rpexy[iy * RNUM + ix] + rpez[iz];
                pe[j] = exp2r(sv);
            }
            union { unsigned w[2]; s16x4 v; } u;
            u.w[0] = cvtpk(pe[0], pe[1]);
            u.w[1] = cvtpk(pe[2], pe[3]);
            pf[qi] = u.v;
        }

        const int kblk = (kabs >> 6) * 128;
        const int koff2 = (kabs & 63) * 2;
        __builtin_amdgcn_s_setprio(1);
#pragma unroll
        for (int qi = 0; qi < 2; ++qi)
            lacc[qi] = __builtin_amdgcn_mfma_f32_16x16x16bf16_1k(
                pf[qi], vone, lacc[qi], 0, 0, 0);
#pragma unroll
        for (int nd = 0; nd < 4; ++nd) {
            int d = nd * 16 + L;
            s16x4 vf = *(const s16x4*)&smem[LDSV + d * 512 + kblk +
                (koff2 ^ ((d & 7) << 4))];
#pragma unroll
            for (int qi = 0; qi < 2; ++qi)
                oacc[qi][nd] = __builtin_amdgcn_mfma_f32_16x16x16bf16_1k(
                    pf[qi], vf, oacc[qi][nd], 0, 0, 0);
        }
        __builtin_amdgcn_s_setprio(0);
    }

    // staging dead; per-wave [16][72] u16 transpose buffer.
    __syncthreads();
    u16* ot = (u16*)&smem[wv * 2304];
#pragma unroll
    for (int qi = 0; qi < 2; ++qi) {
#pragma unroll
        for (int reg = 0; reg < 4; ++reg) {
            float li = rcpr(lacc[qi][reg]);
#pragma unroll
            for (int nd = 0; nd < 4; ++nd)
                ot[(gq * 4 + reg) * 72 + nd * 16 + L] = f2b(oacc[qi][nd][reg] * li);
        }
#pragma unroll
        for (int s = 0; s < 4; ++s) {
            int r = s * 4 + (lane >> 4);
            int c = (lane & 15) * 4;
            u16x4 a = *(const u16x4*)&ot[r * 72 + c];
            int q = q0 + qi * 16 + r;
            *(u16x4*)&oa16[(size_t)(p * KP + q) * CCH + h * DH + c] = a;
        }
    }
}

// ---------------------------------------------------------------------------
// Kernel C: proj GEMM: out = A16 @ (Bh+Bl)^T + bias  (frozen)
// ---------------------------------------------------------------------------
__global__ __launch_bounds__(256, 3) void gemm_proj(
    const u16* __restrict__ A16,
    const u16* __restrict__ Bh, const u16* __restrict__ Bl,
    const float* __restrict__ bias, const int* __restrict__ order,
    float* __restrict__ out)
{
    __shared__ __align__(16) unsigned char smemP[49152];   // 48 KB
    u16* LA  = (u16*)smemP;
    u16* LBh = (u16*)&smemP[16384];
    u16* LBl = (u16*)&smemP[32768];

    const int t = threadIdx.x;
    const int lane = t & 63, wv = t >> 6;
    const int L = lane & 15, gq = lane >> 4;
    const int wr = wv >> 1, wc = wv & 1;

    const int orig = blockIdx.y * 3 + blockIdx.x;
    const int swz  = (orig & 7) * 192 + (orig >> 3);        // bijective (1536%8==0)
    const int n0 = (swz % 3) * 128;
    const int m0 = (swz / 3) * 128;

    f32x4 acc[4][4];
#pragma unroll
    for (int mi = 0; mi < 4; ++mi)
#pragma unroll
        for (int ni = 0; ni < 4; ++ni) acc[mi][ni] = (f32x4)0.f;

    for (int kc = 0; kc < K1; kc += 64) {
        __syncthreads();
#pragma unroll
        for (int i = 0; i < 4; ++i) {
            int ci = i * 256 + t;
            int r = ci >> 3, j = ci & 7;
            int c8 = (j ^ (r & 7)) * 8;
            gll16(A16 + (size_t)(m0 + r) * K1 + kc + c8, LA + ci * 8);
            size_t gb = (size_t)(n0 + r) * K1 + kc + c8;
            gll16(Bh + gb, LBh + ci * 8);
            gll16(Bl + gb, LBl + ci * 8);
        }
        __syncthreads();
#pragma unroll
        for (int ks = 0; ks < 2; ++ks) {
            s16x8 fah[4], fbh[4], fbl[4];
#pragma unroll
            for (int x = 0; x < 4; ++x) {
                int arow = wr * 64 + x * 16 + L;
                int brow = wc * 64 + x * 16 + L;
                int ka  = ((ks * 4 + gq) ^ (arow & 7)) * 8;
                int kb2 = ((ks * 4 + gq) ^ (brow & 7)) * 8;
                fah[x] = *(const s16x8*)&LA[arow * 64 + ka];
                fbh[x] = *(const s16x8*)&LBh[brow * 64 + kb2];
                fbl[x] = *(const s16x8*)&LBl[brow * 64 + kb2];
            }
#pragma unroll
            for (int mi = 0; mi < 4; ++mi)
#pragma unroll
                for (int ni = 0; ni < 4; ++ni) {
                    acc[mi][ni] = __builtin_amdgcn_mfma_f32_16x16x32_bf16(
                        fah[mi], fbh[ni], acc[mi][ni], 0, 0, 0);
                    acc[mi][ni] = __builtin_amdgcn_mfma_f32_16x16x32_bf16(
                        fah[mi], fbl[ni], acc[mi][ni], 0, 0, 0);
                }
        }
    }

    float bfrag[4];
#pragma unroll
    for (int ni = 0; ni < 4; ++ni) bfrag[ni] = bias[n0 + wc * 64 + ni * 16 + L];

    __syncthreads();
    float* otp = (float*)smemP + wv * 1088;   // [16][68] f32 per wave
#pragma unroll
    for (int mi = 0; mi < 4; ++mi) {
#pragma unroll
        for (int reg = 0; reg < 4; ++reg)
#pragma unroll
            for (int ni = 0; ni < 4; ++ni)
                otp[(gq * 4 + reg) * 68 + ni * 16 + L] = acc[mi][ni][reg] + bfrag[ni];
#pragma unroll
        for (int s = 0; s < 4; ++s) {
            int r = s * 4 + (lane >> 4);
            int c = (lane & 15) * 4;
            f32x4 a = *(const f32x4*)&otp[r * 68 + c];
            int j = m0 + wr * 64 + mi * 16 + r;
            float* dst = out + (size_t)order[j] * CCH + n0 + wc * 64 + c;
            *(f32x4*)dst = a;
        }
        __syncthreads();
    }
}

// ---------------------------------------------------------------------------
extern "C" void kernel_launch(void* const* d_in, const int* in_sizes, int n_in,
                              void* d_out, int out_size, void* d_ws, size_t ws_size,
                              hipStream_t stream) {
    const float* feat      = (const float*)d_in[0];
    const float* qkv_w     = (const float*)d_in[1];
    const float* qkv_b     = (const float*)d_in[2];
    const float* proj_w    = (const float*)d_in[3];
    const float* proj_b    = (const float*)d_in[4];
    const float* rpe_table = (const float*)d_in[5];
    const int*   order     = (const int*)d_in[6];
    const int*   gcoord    = (const int*)d_in[8];
    float* out = (float*)d_out;

    const size_t NC = (size_t)NPTS * CCH;
    u16* fh   = (u16*)d_ws;
    u16* qwh  = fh + NC;
    u16* pwh  = qwh + (size_t)1152 * 384;
    u16* pwl  = pwh + (size_t)384 * 384;
    u16* qs   = pwl + (size_t)384 * 384;
    u16* ks   = qs + NC;
    u16* vts  = ks + NC;
    u16* oa16 = vts + NC;
    unsigned* cxy_g = (unsigned*)(oa16 + NC);
    u16* cz_g = (u16*)(cxy_g + NPTS);

    prep_all<<<(NPREP + 255) / 256, 256, 0, stream>>>(
        feat, order, gcoord, qkv_w, proj_w,
        fh, qwh, pwh, pwl, cxy_g, cz_g);

    gemm_qkv<<<dim3(9, NPTS / 128), 256, 0, stream>>>(
        fh, qwh, qkv_b, qs, ks, vts);
    attn_mfma<<<dim3(NPATCH, NH), 512, 0, stream>>>(
        qs, ks, vts, cxy_g, cz_g, rpe_table, oa16);
    gemm_proj<<<dim3(3, NPTS / 128), 256, 0, stream>>>(
        oa16, pwh, pwl, proj_b, order, out);
}